// Round 1
// baseline (823.123 us; speedup 1.0000x reference)
//
#include <hip/hip_runtime.h>
#include <math.h>

#define SDIM 128
#define HID 64
#define DEPTH 4
#define CUTOFF_F 5.0f
#define CHUNK 4096

typedef __attribute__((ext_vector_type(8))) short bf16x8;   // 8 bf16 = 4 VGPRs
typedef __attribute__((ext_vector_type(4))) float f32x4;
typedef float4 __attribute__((aligned(4))) float4_u;        // 4B-aligned float4 load

// fast silu: v_exp + v_rcp
__device__ __forceinline__ float silu_f(float x) {
    float e = __expf(-x);
    return x * __builtin_amdgcn_rcpf(1.0f + e);
}

// Native bf16 convert (RNE) — compiler lowers to v_cvt_pk_bf16_f32 on gfx950.
__device__ __forceinline__ unsigned short f2bf(float x) {
    __bf16 b = (__bf16)x;
    return __builtin_bit_cast(unsigned short, b);
}
__device__ __forceinline__ unsigned int f2bf2(float a, float b) {
    return (unsigned int)f2bf(a) | ((unsigned int)f2bf(b) << 16);
}
__device__ __forceinline__ float bf2f(unsigned short u) {
    return __uint_as_float(((unsigned int)u) << 16);
}

struct f8 { float v[8]; };
__device__ __forceinline__ f8 load8(const float* p) {
    f8 r;
    float4 a = *(const float4*)p;
    float4 b = *(const float4*)(p + 4);
    r.v[0]=a.x; r.v[1]=a.y; r.v[2]=a.z; r.v[3]=a.w;
    r.v[4]=b.x; r.v[5]=b.y; r.v[6]=b.z; r.v[7]=b.w;
    return r;
}
__device__ __forceinline__ bf16x8 pack8(const float* h) {
    bf16x8 o;
#pragma unroll
    for (int j = 0; j < 8; ++j) o[j] = (short)f2bf(h[j]);
    return o;
}
__device__ __forceinline__ void unpack8(bf16x8 b, float* o) {
#pragma unroll
    for (int j = 0; j < 8; ++j)
        o[j] = __uint_as_float(((unsigned int)(unsigned short)b[j]) << 16);
}

// ---------------------------------------------------------------------------
// Index decode + degree histogram.
// ---------------------------------------------------------------------------
__global__ void detect_idx_kernel(const void* ei, int N, int* flag) {
    int lane = threadIdx.x;   // 64 lanes
    const long long* p64 = (const long long*)ei;
    long long v = p64[lane];
    bool ok = (v >= 0 && v < (long long)N);
    unsigned long long m = __ballot(ok);
    if (lane == 0) *flag = (m == ~0ull) ? 1 : 0;
}

__global__ void decode_idx_kernel(const void* ei, int E, int N, const int* flag,
                                  int* __restrict__ srcw, int* __restrict__ dstw,
                                  int* __restrict__ deg_i) {
    int i = blockIdx.x * blockDim.x + threadIdx.x;
    if (i >= 2 * E) return;
    int v;
    if (*flag) v = (int)((const long long*)ei)[i];
    else       v = ((const int*)ei)[i];
    v = min(max(v, 0), N - 1);
    if (i < E) {
        srcw[i] = v;
    } else {
        dstw[i - E] = v;
        atomicAdd(&deg_i[v], 1);
    }
}

// ---------------------------------------------------------------------------
// 3-phase parallel exclusive scan: deg_i -> row_start[0..N]
// ---------------------------------------------------------------------------
__global__ __launch_bounds__(256) void scan1_kernel(const int* __restrict__ deg_i,
                                                    int* __restrict__ part, int N) {
    __shared__ int wsum[4];
    int b = blockIdx.x, t = threadIdx.x;
    int base = b * CHUNK;
    int sum = 0;
    for (int i = t; i < CHUNK; i += 256) {
        int idx = base + i;
        sum += (idx < N) ? deg_i[idx] : 0;
    }
#pragma unroll
    for (int off = 32; off; off >>= 1) sum += __shfl_down(sum, off, 64);
    if ((t & 63) == 0) wsum[t >> 6] = sum;
    __syncthreads();
    if (t == 0) part[b] = wsum[0] + wsum[1] + wsum[2] + wsum[3];
}

__global__ void scan2_kernel(int* __restrict__ part, int* __restrict__ row_start,
                             int B1, int N) {
    int t = threadIdx.x;   // 64 threads
    int v = (t < B1) ? part[t] : 0;
    int incl = v;
#pragma unroll
    for (int off = 1; off < 64; off <<= 1) {
        int x = __shfl_up(incl, off, 64);
        if (t >= off) incl += x;
    }
    if (t < B1) part[t] = incl - v;      // exclusive
    if (t == 63) row_start[N] = incl;    // grand total
}

__global__ __launch_bounds__(256) void scan3_kernel(const int* __restrict__ deg_i,
                                                    const int* __restrict__ part,
                                                    int* __restrict__ row_start, int N) {
    __shared__ int wsum[4];
    __shared__ int carry_s;
    int b = blockIdx.x, t = threadIdx.x;
    int lane = t & 63, w = t >> 6;
    if (t == 0) carry_s = part[b];
    __syncthreads();
    int base0 = b * CHUNK;
    for (int base = base0; base < base0 + CHUNK; base += 256) {
        int i = base + t;
        int v = (i < N) ? deg_i[i] : 0;
        int incl = v;
#pragma unroll
        for (int off = 1; off < 64; off <<= 1) {
            int x = __shfl_up(incl, off, 64);
            if (lane >= off) incl += x;
        }
        if (lane == 63) wsum[w] = incl;
        __syncthreads();
        int wpre = 0;
#pragma unroll
        for (int k = 0; k < 4; ++k) if (k < w) wpre += wsum[k];
        int total = wsum[0] + wsum[1] + wsum[2] + wsum[3];
        int carry = carry_s;
        if (i < N) row_start[i] = carry + wpre + incl - v;
        __syncthreads();
        if (t == 0) carry_s = carry + total;
        __syncthreads();
    }
}

// ---------------------------------------------------------------------------
// Scatter: dst-sorted permutation; one packed 32B record per edge.
// ---------------------------------------------------------------------------
__global__ void scatter_kernel(const int* __restrict__ srcw, const int* __restrict__ dstw,
                               const float* __restrict__ dvec, const float* __restrict__ rvec,
                               const int* __restrict__ row_start, int* __restrict__ cursor,
                               float* __restrict__ rec, int E) {
    int e = blockIdx.x * blockDim.x + threadIdx.x;
    if (e >= E) return;
    int dd = dstw[e];
    int ofs = atomicAdd(&cursor[dd], 1);
    int pos = row_start[dd] + ofs;
    float dv = dvec[e];
    float c = 0.5f * (cosf(3.14159265358979323846f * dv * (1.0f / CUTOFF_F)) + 1.0f);
    c = (dv < CUTOFF_F) ? c : 0.0f;
    float4 r0 = make_float4(__int_as_float(srcw[e]), __int_as_float(dd), dv, c);
    float4 r1 = make_float4(rvec[(size_t)e * 3 + 0], rvec[(size_t)e * 3 + 1],
                            rvec[(size_t)e * 3 + 2], 0.0f);
    *(float4*)(rec + (size_t)pos * 8)     = r0;
    *(float4*)(rec + (size_t)pos * 8 + 4) = r1;
}

// ---------------------------------------------------------------------------
// Weight transpose+cast to bf16 [n][k] for MFMA B-operands.
// ---------------------------------------------------------------------------
__global__ __launch_bounds__(256) void wprep_kernel(
    const float* __restrict__ We1, const float* __restrict__ We2,
    const float* __restrict__ Wv,  const float* __restrict__ Wn1,
    const float* __restrict__ Wn2,
    unsigned short* __restrict__ We1t, unsigned short* __restrict__ We2t,
    unsigned short* __restrict__ Wvt,  unsigned short* __restrict__ Wn1t,
    unsigned short* __restrict__ Wn2t) {
    int l = blockIdx.x, t = threadIdx.x;
    const float* W2 = We2 + (size_t)l * HID * HID;
    unsigned short* T2 = We2t + (size_t)l * HID * HID;
    for (int idx = t; idx < HID * HID; idx += 256) {
        int n = idx >> 6, k = idx & 63;
        T2[n * 64 + k] = f2bf(W2[k * HID + n]);
    }
    const float* Wvl = Wv + (size_t)l * HID * 6;
    unsigned short* Tv = Wvt + (size_t)l * 16 * 64;
    for (int idx = t; idx < 16 * 64; idx += 256) {
        int n = idx >> 6, k = idx & 63;
        Tv[idx] = (n < 6) ? f2bf(Wvl[k * 6 + n]) : (unsigned short)0;
    }
    const float* W1 = We1 + (size_t)l * 257 * 64;
    unsigned short* T1 = We1t + (size_t)l * 128 * 128;
    for (int idx = t; idx < 128 * 128; idx += 256) {
        int n = idx >> 7, k = idx & 127;
        float w = (n < 64) ? W1[(size_t)k * 64 + n] : W1[(size_t)(k + 128) * 64 + (n - 64)];
        T1[n * 128 + k] = f2bf(w);
    }
    const float* Wn1l = Wn1 + (size_t)l * 192 * 64;
    unsigned short* Tn1 = Wn1t + (size_t)l * 64 * 192;
    for (int idx = t; idx < 64 * 192; idx += 256) {
        int n = idx / 192, k = idx - n * 192;
        Tn1[idx] = f2bf(Wn1l[(size_t)k * 64 + n]);
    }
    const float* Wn2l = Wn2 + (size_t)l * 64 * 128;
    unsigned short* Tn2 = Wn2t + (size_t)l * 128 * 64;
    for (int idx = t; idx < 128 * 64; idx += 256) {
        int n = idx >> 6, k = idx & 63;
        Tn2[idx] = f2bf(Wn2l[(size_t)k * 128 + n]);
    }
}

// ---------------------------------------------------------------------------
// node_pre (layer 0 only): [Pa|Pb] = s @ [We1a|We1b] (+be1 on Pa), bf16 out
// ---------------------------------------------------------------------------
__global__ __launch_bounds__(256) void node_pre_kernel(
    const float* __restrict__ s, const unsigned short* __restrict__ We1t,
    const float* __restrict__ be1,
    unsigned short* __restrict__ Pa, unsigned short* __restrict__ Pb, int N)
{
    __shared__ unsigned short sa[64 * 136];
    int t = threadIdx.x;
    int n0 = blockIdx.x * 64;
    for (int idx = t; idx < 64 * 32; idx += 256) {
        int rn = idx >> 5, c4 = (idx & 31) << 2;
        int n = n0 + rn;
        float4 val = make_float4(0.f, 0.f, 0.f, 0.f);
        if (n < N) val = *(const float4*)(s + (size_t)n * SDIM + c4);
        *(uint2*)(sa + rn * 136 + c4) = make_uint2(f2bf2(val.x, val.y), f2bf2(val.z, val.w));
    }
    __syncthreads();
    int lane = t & 63, w = t >> 6;
    int lm = lane & 15, lq = lane >> 4;
    int m0 = w * 16, rm = m0 + lm;

    bf16x8 af[4];
#pragma unroll
    for (int kc = 0; kc < 4; ++kc)
        af[kc] = *(const bf16x8*)(sa + rm * 136 + kc * 32 + lq * 8);

#pragma unroll
    for (int ct = 0; ct < 8; ++ct) {
        int col = ct * 16 + lm;
        f32x4 acc = {0.f, 0.f, 0.f, 0.f};
#pragma unroll
        for (int kc = 0; kc < 4; ++kc) {
            bf16x8 b = *(const bf16x8*)(We1t + (size_t)col * 128 + kc * 32 + lq * 8);
            acc = __builtin_amdgcn_mfma_f32_16x16x32_bf16(af[kc], b, acc, 0, 0, 0);
        }
        float bias = (ct < 4) ? be1[col] : 0.0f;
#pragma unroll
        for (int g = 0; g < 4; ++g) {
            int n = n0 + m0 + lq * 4 + g;
            if (n < N) {
                if (ct < 4) Pa[(size_t)n * HID + col]        = f2bf(acc[g] + bias);
                else        Pb[(size_t)n * HID + (col - 64)] = f2bf(acc[g]);
            }
        }
    }
}

// ---------------------------------------------------------------------------
// Fused edge kernel (dst-sorted, segmented reduction, boundary atomics).
// recb holds raw 32B records (all-lane staging); hb bf16 stride 72;
// v[src] staged 4-lanes-per-row; gates MFMA operand-swapped (gate-major out).
// ---------------------------------------------------------------------------
__global__ __launch_bounds__(256) void edge_kernel(
    const float* __restrict__ rec,
    const unsigned short* __restrict__ Pa, const unsigned short* __restrict__ Pb,
    const float* __restrict__ wd,
    const unsigned short* __restrict__ We2t, const float* __restrict__ be2,
    const unsigned short* __restrict__ Wvt, const float* __restrict__ bv,
    const float* __restrict__ v,
    float* __restrict__ agg_s, float* __restrict__ agg_v, int E)
{
    __shared__ unsigned short hb[64 * 72];   // h bf16, stride 72 shorts (144B)
    __shared__ float gl[64 * 8];
    __shared__ float vb[64 * 12];            // v[src] rows (9 used, pad 12)
    __shared__ float recb[64 * 8];           // raw records: src,dst,d,C,rx,ry,rz,-
    int t = threadIdx.x;
    int e0 = blockIdx.x * 64;

    // ---- stage rec with all 256 lanes (2 floats each) ----
    if (e0 + 64 <= E) {
        float2 rv = *(const float2*)(rec + (size_t)e0 * 8 + 2 * t);
        *(float2*)(recb + 2 * t) = rv;
    } else {
        int r = t >> 2, c = (t & 3) * 2;
        int e = e0 + r;
        int ec = (e < E) ? e : (E - 1);
        float a  = rec[(size_t)ec * 8 + c];
        float b2 = rec[(size_t)ec * 8 + c + 1];
        if (e >= E && c == 2) b2 = 0.0f;     // zero C for padded rows
        recb[2 * t]     = a;
        recb[2 * t + 1] = b2;
    }
    __syncthreads();

    int lane = t & 63;
    int w    = t >> 6;
    int lm = lane & 15, lq = lane >> 4;
    int m0 = w * 16;
    int rm = m0 + lm;
    int ka = lq * 8;
    int kb = 32 + lq * 8;

    // ---- stage v[src] rows into LDS, 4 lanes per row (consumed after hb barrier) ----
    {
        int r = t >> 2, p = t & 3;
        const float* vr = v + (size_t)__float_as_int(recb[r * 8]) * 9;
        if (p < 2) {
            float4_u a = *(const float4_u*)(vr + p * 4);
            vb[r * 12 + p * 4 + 0] = a.x;
            vb[r * 12 + p * 4 + 1] = a.y;
            vb[r * 12 + p * 4 + 2] = a.z;
            vb[r * 12 + p * 4 + 3] = a.w;
        } else if (p == 2) {
            vb[r * 12 + 8] = vr[8];
        }
    }
    // ---- prefetch Wv^T fragments (A-operand of gates MFMA) ----
    bf16x8 wv0 = *(const bf16x8*)(Wvt + (size_t)lm * 64 + ka);
    bf16x8 wv1 = *(const bf16x8*)(Wvt + (size_t)lm * 64 + kb);

    // ---- phase 1: h1 in MFMA A-layout, registers only (bf16 gathers) ----
    bf16x8 afr0, afr1;
    {
        int srcr = __float_as_int(recb[rm * 8 + 0]);
        int dstr = __float_as_int(recb[rm * 8 + 1]);
        float dv = recb[rm * 8 + 2];
        const unsigned short* pa = Pa + (size_t)dstr * HID;
        const unsigned short* pb = Pb + (size_t)srcr * HID;
        bf16x8 ba0 = *(const bf16x8*)(pa + ka);
        bf16x8 bb0 = *(const bf16x8*)(pb + ka);
        bf16x8 ba1 = *(const bf16x8*)(pa + kb);
        bf16x8 bb1 = *(const bf16x8*)(pb + kb);
        f8 xw = load8(wd + ka), yw = load8(wd + kb);
        float fa[8], fb[8], h1[8];
        unpack8(ba0, fa); unpack8(bb0, fb);
#pragma unroll
        for (int j = 0; j < 8; ++j) h1[j] = silu_f(fa[j] + fb[j] + dv * xw.v[j]);
        afr0 = pack8(h1);
        unpack8(ba1, fa); unpack8(bb1, fb);
#pragma unroll
        for (int j = 0; j < 8; ++j) h1[j] = silu_f(fa[j] + fb[j] + dv * yw.v[j]);
        afr1 = pack8(h1);
    }

    // ---- phase 2: h = silu(h1@We2+be2)*C via MFMA -> hb bf16 ----
    float cc[4];
#pragma unroll
    for (int g = 0; g < 4; ++g) cc[g] = recb[(m0 + lq * 4 + g) * 8 + 3];
#pragma unroll
    for (int t4 = 0; t4 < 4; ++t4) {
        int col = t4 * 16 + lm;
        bf16x8 b0 = *(const bf16x8*)(We2t + (size_t)col * 64 + ka);
        bf16x8 b1 = *(const bf16x8*)(We2t + (size_t)col * 64 + kb);
        f32x4 a = {0.f, 0.f, 0.f, 0.f};
        a = __builtin_amdgcn_mfma_f32_16x16x32_bf16(afr0, b0, a, 0, 0, 0);
        a = __builtin_amdgcn_mfma_f32_16x16x32_bf16(afr1, b1, a, 0, 0, 0);
        float bias = be2[col];
#pragma unroll
        for (int g = 0; g < 4; ++g) {
            int er = m0 + lq * 4 + g;
            hb[er * 72 + col] = f2bf(silu_f(a[g] + bias) * cc[g]);
        }
    }
    __syncthreads();

    // ---- gates = (Wv^T @ h^T): operand-swapped MFMA, gate-major per lane ----
    {
        bf16x8 hb0 = *(const bf16x8*)(hb + rm * 72 + ka);
        bf16x8 hb1 = *(const bf16x8*)(hb + rm * 72 + kb);
        f32x4 ga = {0.f, 0.f, 0.f, 0.f};
        ga = __builtin_amdgcn_mfma_f32_16x16x32_bf16(wv0, hb0, ga, 0, 0, 0);
        ga = __builtin_amdgcn_mfma_f32_16x16x32_bf16(wv1, hb1, ga, 0, 0, 0);
        // D[m=gate lq*4+g][n=edge m0+lm]
        int er2 = m0 + lm;
        if (lq == 0) {
            float4_u bb = *(const float4_u*)bv;
            *(float4*)(gl + er2 * 8) =
                make_float4(ga[0] + bb.x, ga[1] + bb.y, ga[2] + bb.z, ga[3] + bb.w);
        } else if (lq == 1) {
            gl[er2 * 8 + 4] = ga[0] + bv[4];
            gl[er2 * 8 + 5] = ga[1] + bv[5];
        }
    }

    // ---- agg_s: segmented column-sum over dst runs (bf16 reads) ----
    {
        int c = t & 63, seg = t >> 6;
        int r0s = seg * 16;
        float acc = 0.f;
        int cur = __float_as_int(recb[r0s * 8 + 1]);
#pragma unroll 4
        for (int r = r0s; r < r0s + 16; ++r) {
            int dr = __float_as_int(recb[r * 8 + 1]);
            if (dr != cur) {
                atomicAdd(&agg_s[(size_t)cur * HID + c], acc);
                acc = 0.f; cur = dr;
            }
            acc += bf2f(hb[r * 72 + c]);
        }
        atomicAdd(&agg_s[(size_t)cur * HID + c], acc);
    }
    __syncthreads();

    // ---- agg_v: mv = v[src]*g1 + r*g2, segmented sum (v rows from LDS) ----
    if (t < 144) {
        int seg = t / 9;
        int c = t - seg * 9;
        int i = c / 3, j = c - i * 3;
        int r0v = seg * 4;
        float acc = 0.f;
        int cur = __float_as_int(recb[r0v * 8 + 1]);
#pragma unroll
        for (int r = 0; r < 4; ++r) {
            int rr = r0v + r;
            int dr = __float_as_int(recb[rr * 8 + 1]);
            if (dr != cur) {
                atomicAdd(&agg_v[(size_t)cur * 9 + c], acc);
                acc = 0.f; cur = dr;
            }
            if (e0 + rr < E) {
                acc += vb[rr * 12 + c] * gl[rr * 8 + j]
                     + recb[rr * 8 + 4 + i] * gl[rr * 8 + 3 + j];
            }
        }
        atomicAdd(&agg_v[(size_t)cur * 9 + c], acc);
    }
}

// ---------------------------------------------------------------------------
// Fused node kernel: u = silu([s,agg_s]@Wn1+bn1); s += u@Wn2+bn2;
// v += agg_v/deg; then (do_pre) [Pa|Pb] = s_new @ We1(l+1) (bf16 out).
// Zeroes agg_s/agg_v for the next layer (zero-after-read).
// ---------------------------------------------------------------------------
__global__ __launch_bounds__(256) void node_fused_kernel(
    float* __restrict__ s, float* __restrict__ vout,
    float* __restrict__ agg_s, float* __restrict__ agg_v,
    const int* __restrict__ row_start,
    const unsigned short* __restrict__ Wn1t, const float* __restrict__ bn1,
    const unsigned short* __restrict__ Wn2t, const float* __restrict__ bn2,
    const unsigned short* __restrict__ We1tn, const float* __restrict__ be1n,
    unsigned short* __restrict__ Pa, unsigned short* __restrict__ Pb,
    int N, int do_pre)
{
    __shared__ unsigned short xa[64 * 200];  // phase A: [s|agg_s]; phase B alias: s_new (stride 136)
    __shared__ unsigned short ub[64 * 72];
    int t = threadIdx.x;
    int n0 = blockIdx.x * 64;
    for (int idx = t; idx < 64 * 32; idx += 256) {
        int rn = idx >> 5, c4 = (idx & 31) << 2;
        int n = n0 + rn;
        float4 val = make_float4(0.f, 0.f, 0.f, 0.f);
        if (n < N) val = *(const float4*)(s + (size_t)n * SDIM + c4);
        *(uint2*)(xa + rn * 200 + c4) = make_uint2(f2bf2(val.x, val.y), f2bf2(val.z, val.w));
    }
    for (int idx = t; idx < 64 * 16; idx += 256) {
        int rn = idx >> 4, c4 = (idx & 15) << 2;
        int n = n0 + rn;
        float4 val = make_float4(0.f, 0.f, 0.f, 0.f);
        if (n < N) {
            float* ap = agg_s + (size_t)n * HID + c4;
            val = *(const float4*)ap;
            *(float4*)ap = make_float4(0.f, 0.f, 0.f, 0.f);   // zero for next layer
        }
        *(uint2*)(xa + rn * 200 + 128 + c4) = make_uint2(f2bf2(val.x, val.y), f2bf2(val.z, val.w));
    }
    __syncthreads();

    int lane = t & 63, w = t >> 6;
    int lm = lane & 15, lq = lane >> 4;
    int m0 = w * 16, rm = m0 + lm;

    // ---- GEMM1: u = silu(x @ Wn1 + bn1) ----
    bf16x8 af[6];
#pragma unroll
    for (int kc = 0; kc < 6; ++kc)
        af[kc] = *(const bf16x8*)(xa + rm * 200 + kc * 32 + lq * 8);

#pragma unroll
    for (int ct = 0; ct < 4; ++ct) {
        int col = ct * 16 + lm;
        f32x4 acc = {0.f, 0.f, 0.f, 0.f};
#pragma unroll
        for (int kc = 0; kc < 6; ++kc) {
            bf16x8 b = *(const bf16x8*)(Wn1t + (size_t)col * 192 + kc * 32 + lq * 8);
            acc = __builtin_amdgcn_mfma_f32_16x16x32_bf16(af[kc], b, acc, 0, 0, 0);
        }
        float bias = bn1[col];
#pragma unroll
        for (int g = 0; g < 4; ++g) {
            int er = m0 + lq * 4 + g;
            ub[er * 72 + col] = f2bf(silu_f(acc[g] + bias));
        }
    }
    __syncthreads();   // ub ready; xa reads done -> reusable

    // ---- GEMM2: s_new = s + u @ Wn2 + bn2 ; stash s_new bf16 in LDS ----
    unsigned short* sa = xa;   // alias (stride 136)
    bf16x8 uf[2];
#pragma unroll
    for (int kc = 0; kc < 2; ++kc)
        uf[kc] = *(const bf16x8*)(ub + rm * 72 + kc * 32 + lq * 8);

#pragma unroll
    for (int ct = 0; ct < 8; ++ct) {
        int col = ct * 16 + lm;
        f32x4 acc = {0.f, 0.f, 0.f, 0.f};
#pragma unroll
        for (int kc = 0; kc < 2; ++kc) {
            bf16x8 b = *(const bf16x8*)(Wn2t + (size_t)col * 64 + kc * 32 + lq * 8);
            acc = __builtin_amdgcn_mfma_f32_16x16x32_bf16(uf[kc], b, acc, 0, 0, 0);
        }
        float bias = bn2[col];
#pragma unroll
        for (int g = 0; g < 4; ++g) {
            int er = m0 + lq * 4 + g;
            int n = n0 + er;
            if (n < N) {
                float* sp = s + (size_t)n * SDIM + col;
                float sv = *sp + acc[g] + bias;
                *sp = sv;
                sa[er * 136 + col] = f2bf(sv);
            } else {
                sa[er * 136 + col] = 0;
            }
        }
    }
    __syncthreads();   // sa ready

    // ---- pre-GEMM for next layer: [Pa|Pb] = s_new @ We1(l+1) (bf16 out) ----
    if (do_pre) {
        bf16x8 pf[4];
#pragma unroll
        for (int kc = 0; kc < 4; ++kc)
            pf[kc] = *(const bf16x8*)(sa + rm * 136 + kc * 32 + lq * 8);

#pragma unroll
        for (int ct = 0; ct < 8; ++ct) {
            int col = ct * 16 + lm;
            f32x4 acc = {0.f, 0.f, 0.f, 0.f};
#pragma unroll
            for (int kc = 0; kc < 4; ++kc) {
                bf16x8 b = *(const bf16x8*)(We1tn + (size_t)col * 128 + kc * 32 + lq * 8);
                acc = __builtin_amdgcn_mfma_f32_16x16x32_bf16(pf[kc], b, acc, 0, 0, 0);
            }
            float bias = (ct < 4) ? be1n[col] : 0.0f;
#pragma unroll
            for (int g = 0; g < 4; ++g) {
                int n = n0 + m0 + lq * 4 + g;
                if (n < N) {
                    if (ct < 4) Pa[(size_t)n * HID + col]        = f2bf(acc[g] + bias);
                    else        Pb[(size_t)n * HID + (col - 64)] = f2bf(acc[g]);
                }
            }
        }
    }

    // ---- v += agg_v / max(deg,1) ; zero agg_v for next layer ----
    for (int idx = t; idx < 64 * 9; idx += 256) {
        int rn = idx / 9, c = idx - rn * 9;
        int n2 = n0 + rn;
        if (n2 < N) {
            float av = agg_v[(size_t)n2 * 9 + c];
            agg_v[(size_t)n2 * 9 + c] = 0.f;
            float dg = fmaxf((float)(row_start[n2 + 1] - row_start[n2]), 1.0f);
            vout[(size_t)n2 * 9 + c] += av / dg;
        }
    }
}

extern "C" void kernel_launch(void* const* d_in, const int* in_sizes, int n_in,
                              void* d_out, int out_size, void* d_ws, size_t ws_size,
                              hipStream_t stream)
{
    const float* s_in  = (const float*)d_in[0];
    const float* v_in  = (const float*)d_in[1];
    const void*  ei    = d_in[2];
    const float* d_vec = (const float*)d_in[3];
    const float* r_vec = (const float*)d_in[4];
    const float* We1 = (const float*)d_in[6];
    const float* be1 = (const float*)d_in[7];
    const float* We2 = (const float*)d_in[8];
    const float* be2 = (const float*)d_in[9];
    const float* Wn1 = (const float*)d_in[10];
    const float* bn1 = (const float*)d_in[11];
    const float* Wn2 = (const float*)d_in[12];
    const float* bn2 = (const float*)d_in[13];
    const float* Wv  = (const float*)d_in[14];
    const float* bv  = (const float*)d_in[15];

    int N = in_sizes[0] / SDIM;
    int E = in_sizes[3];

    float* out_s = (float*)d_out;
    float* out_v = out_s + (size_t)N * SDIM;

    // ------ workspace layout (32B-aligned blocks) ------
    char* wp = (char*)d_ws;
    auto alloc = [&wp](size_t bytes) -> char* {
        char* p = wp;
        wp += (bytes + 31) & ~(size_t)31;
        return p;
    };
    float* rec       = (float*)alloc((size_t)E * 8 * 4);
    unsigned short* Pa = (unsigned short*)alloc((size_t)N * HID * 2);
    unsigned short* Pb = (unsigned short*)alloc((size_t)N * HID * 2);
    float* agg_s     = (float*)alloc((size_t)N * HID * 4);   // contiguous with agg_v
    float* agg_v     = (float*)alloc((size_t)N * 9 * 4);
    int*   deg_i     = (int*)alloc((size_t)N * 4);           // contiguous with cursor
    int*   cursor    = (int*)alloc((size_t)N * 4);
    int*   row_start = (int*)alloc((size_t)(N + 1) * 4);
    int*   part      = (int*)alloc(64 * 4);
    int*   flag      = (int*)alloc(16);
    int*   srcw      = (int*)alloc((size_t)E * 4);
    int*   dstw      = (int*)alloc((size_t)E * 4);
    unsigned short* We2t = (unsigned short*)alloc((size_t)DEPTH * HID * HID * 2);
    unsigned short* Wvt  = (unsigned short*)alloc((size_t)DEPTH * 16 * 64 * 2);
    unsigned short* We1t = (unsigned short*)alloc((size_t)DEPTH * 128 * 128 * 2);
    unsigned short* Wn1t = (unsigned short*)alloc((size_t)DEPTH * 64 * 192 * 2);
    unsigned short* Wn2t = (unsigned short*)alloc((size_t)DEPTH * 128 * 64 * 2);

    hipMemcpyAsync(out_s, s_in, (size_t)N * SDIM * sizeof(float),
                   hipMemcpyDeviceToDevice, stream);
    hipMemcpyAsync(out_v, v_in, (size_t)N * 9 * sizeof(float),
                   hipMemcpyDeviceToDevice, stream);

    // ------ one-time prep ------
    detect_idx_kernel<<<1, 64, 0, stream>>>(ei, N, flag);
    hipMemsetAsync(deg_i, 0, (size_t)N * 2 * sizeof(int), stream);    // deg_i + cursor
    hipMemsetAsync(agg_s, 0, (size_t)N * (HID + 9) * sizeof(float), stream);
    decode_idx_kernel<<<(2 * E + 255) / 256, 256, 0, stream>>>(ei, E, N, flag,
                                                               srcw, dstw, deg_i);
    int B1 = (N + CHUNK - 1) / CHUNK;
    scan1_kernel<<<B1, 256, 0, stream>>>(deg_i, part, N);
    scan2_kernel<<<1, 64, 0, stream>>>(part, row_start, B1, N);
    scan3_kernel<<<B1, 256, 0, stream>>>(deg_i, part, row_start, N);
    scatter_kernel<<<(E + 255) / 256, 256, 0, stream>>>(srcw, dstw, d_vec, r_vec,
                                                        row_start, cursor, rec, E);
    wprep_kernel<<<DEPTH, 256, 0, stream>>>(We1, We2, Wv, Wn1, Wn2,
                                            We1t, We2t, Wvt, Wn1t, Wn2t);

    int nb_n = (N + 63) / 64;
    int nb_e = (E + 63) / 64;
    node_pre_kernel<<<nb_n, 256, 0, stream>>>(out_s, We1t, be1, Pa, Pb, N);
    for (int l = 0; l < DEPTH; ++l) {
        int ln = (l + 1 < DEPTH) ? (l + 1) : 0;
        const float* We1_l = We1 + (size_t)l * 257 * 64;
        const float* be2_l = be2 + (size_t)l * 64;
        const float* bn1_l = bn1 + (size_t)l * 64;
        const float* bn2_l = bn2 + (size_t)l * 128;
        const float* bv_l  = bv  + (size_t)l * 6;
        const float* be1_n = be1 + (size_t)ln * 64;
        const unsigned short* We2t_l = We2t + (size_t)l * HID * HID;
        const unsigned short* Wvt_l  = Wvt  + (size_t)l * 16 * 64;
        const unsigned short* Wn1t_l = Wn1t + (size_t)l * 64 * 192;
        const unsigned short* Wn2t_l = Wn2t + (size_t)l * 128 * 64;
        const unsigned short* We1t_n = We1t + (size_t)ln * 128 * 128;

        edge_kernel<<<nb_e, 256, 0, stream>>>(rec, Pa, Pb,
                                              We1_l + 256 * 64,
                                              We2t_l, be2_l, Wvt_l, bv_l,
                                              out_v, agg_s, agg_v, E);
        node_fused_kernel<<<nb_n, 256, 0, stream>>>(out_s, out_v, agg_s, agg_v,
                                                    row_start,
                                                    Wn1t_l, bn1_l, Wn2t_l, bn2_l,
                                                    We1t_n, be1_n, Pa, Pb,
                                                    N, (l + 1 < DEPTH) ? 1 : 0);
    }
}

// Round 2
// 815.278 us; speedup vs baseline: 1.0096x; 1.0096x over previous
//
#include <hip/hip_runtime.h>
#include <math.h>

#define SDIM 128
#define HID 64
#define DEPTH 4
#define CUTOFF_F 5.0f
#define CHUNK 4096

typedef __attribute__((ext_vector_type(8))) short bf16x8;   // 8 bf16 = 4 VGPRs
typedef __attribute__((ext_vector_type(4))) float f32x4;
typedef float4 __attribute__((aligned(4))) float4_u;        // 4B-aligned float4 load

// fast silu: v_exp + v_rcp
__device__ __forceinline__ float silu_f(float x) {
    float e = __expf(-x);
    return x * __builtin_amdgcn_rcpf(1.0f + e);
}

// Native bf16 convert (RNE) — lowers to v_cvt_pk_bf16_f32 on gfx950.
__device__ __forceinline__ unsigned short f2bf(float x) {
    __bf16 b = (__bf16)x;
    return __builtin_bit_cast(unsigned short, b);
}
__device__ __forceinline__ unsigned int f2bf2(float a, float b) {
    return (unsigned int)f2bf(a) | ((unsigned int)f2bf(b) << 16);
}
__device__ __forceinline__ float bf2f(unsigned short u) {
    return __uint_as_float(((unsigned int)u) << 16);
}

struct f8 { float v[8]; };
__device__ __forceinline__ f8 load8(const float* p) {
    f8 r;
    float4 a = *(const float4*)p;
    float4 b = *(const float4*)(p + 4);
    r.v[0]=a.x; r.v[1]=a.y; r.v[2]=a.z; r.v[3]=a.w;
    r.v[4]=b.x; r.v[5]=b.y; r.v[6]=b.z; r.v[7]=b.w;
    return r;
}
__device__ __forceinline__ bf16x8 pack8(const float* h) {
    bf16x8 o;
#pragma unroll
    for (int j = 0; j < 8; ++j) o[j] = (short)f2bf(h[j]);
    return o;
}
__device__ __forceinline__ void unpack8(bf16x8 b, float* o) {
#pragma unroll
    for (int j = 0; j < 8; ++j)
        o[j] = __uint_as_float(((unsigned int)(unsigned short)b[j]) << 16);
}

// ---------------------------------------------------------------------------
// Index decode + degree histogram.
// ---------------------------------------------------------------------------
__global__ void detect_idx_kernel(const void* ei, int N, int* flag) {
    int lane = threadIdx.x;   // 64 lanes
    const long long* p64 = (const long long*)ei;
    long long v = p64[lane];
    bool ok = (v >= 0 && v < (long long)N);
    unsigned long long m = __ballot(ok);
    if (lane == 0) *flag = (m == ~0ull) ? 1 : 0;
}

__global__ void decode_idx_kernel(const void* ei, int E, int N, const int* flag,
                                  int* __restrict__ srcw, int* __restrict__ dstw,
                                  int* __restrict__ deg_i) {
    int i = blockIdx.x * blockDim.x + threadIdx.x;
    if (i >= 2 * E) return;
    int v;
    if (*flag) v = (int)((const long long*)ei)[i];
    else       v = ((const int*)ei)[i];
    v = min(max(v, 0), N - 1);
    if (i < E) {
        srcw[i] = v;
    } else {
        dstw[i - E] = v;
        atomicAdd(&deg_i[v], 1);
    }
}

// ---------------------------------------------------------------------------
// 3-phase parallel exclusive scan: deg_i -> row_start[0..N]
// ---------------------------------------------------------------------------
__global__ __launch_bounds__(256) void scan1_kernel(const int* __restrict__ deg_i,
                                                    int* __restrict__ part, int N) {
    __shared__ int wsum[4];
    int b = blockIdx.x, t = threadIdx.x;
    int base = b * CHUNK;
    int sum = 0;
    for (int i = t; i < CHUNK; i += 256) {
        int idx = base + i;
        sum += (idx < N) ? deg_i[idx] : 0;
    }
#pragma unroll
    for (int off = 32; off; off >>= 1) sum += __shfl_down(sum, off, 64);
    if ((t & 63) == 0) wsum[t >> 6] = sum;
    __syncthreads();
    if (t == 0) part[b] = wsum[0] + wsum[1] + wsum[2] + wsum[3];
}

__global__ void scan2_kernel(int* __restrict__ part, int* __restrict__ row_start,
                             int B1, int N) {
    int t = threadIdx.x;   // 64 threads
    int v = (t < B1) ? part[t] : 0;
    int incl = v;
#pragma unroll
    for (int off = 1; off < 64; off <<= 1) {
        int x = __shfl_up(incl, off, 64);
        if (t >= off) incl += x;
    }
    if (t < B1) part[t] = incl - v;      // exclusive
    if (t == 63) row_start[N] = incl;    // grand total
}

__global__ __launch_bounds__(256) void scan3_kernel(const int* __restrict__ deg_i,
                                                    const int* __restrict__ part,
                                                    int* __restrict__ row_start, int N) {
    __shared__ int wsum[4];
    __shared__ int carry_s;
    int b = blockIdx.x, t = threadIdx.x;
    int lane = t & 63, w = t >> 6;
    if (t == 0) carry_s = part[b];
    __syncthreads();
    int base0 = b * CHUNK;
    for (int base = base0; base < base0 + CHUNK; base += 256) {
        int i = base + t;
        int v = (i < N) ? deg_i[i] : 0;
        int incl = v;
#pragma unroll
        for (int off = 1; off < 64; off <<= 1) {
            int x = __shfl_up(incl, off, 64);
            if (lane >= off) incl += x;
        }
        if (lane == 63) wsum[w] = incl;
        __syncthreads();
        int wpre = 0;
#pragma unroll
        for (int k = 0; k < 4; ++k) if (k < w) wpre += wsum[k];
        int total = wsum[0] + wsum[1] + wsum[2] + wsum[3];
        int carry = carry_s;
        if (i < N) row_start[i] = carry + wpre + incl - v;
        __syncthreads();
        if (t == 0) carry_s = carry + total;
        __syncthreads();
    }
}

// ---------------------------------------------------------------------------
// Scatter: dst-sorted permutation; one packed 32B record per edge.
// ---------------------------------------------------------------------------
__global__ void scatter_kernel(const int* __restrict__ srcw, const int* __restrict__ dstw,
                               const float* __restrict__ dvec, const float* __restrict__ rvec,
                               const int* __restrict__ row_start, int* __restrict__ cursor,
                               float* __restrict__ rec, int E) {
    int e = blockIdx.x * blockDim.x + threadIdx.x;
    if (e >= E) return;
    int dd = dstw[e];
    int ofs = atomicAdd(&cursor[dd], 1);
    int pos = row_start[dd] + ofs;
    float dv = dvec[e];
    float c = 0.5f * (cosf(3.14159265358979323846f * dv * (1.0f / CUTOFF_F)) + 1.0f);
    c = (dv < CUTOFF_F) ? c : 0.0f;
    float4 r0 = make_float4(__int_as_float(srcw[e]), __int_as_float(dd), dv, c);
    float4 r1 = make_float4(rvec[(size_t)e * 3 + 0], rvec[(size_t)e * 3 + 1],
                            rvec[(size_t)e * 3 + 2], 0.0f);
    *(float4*)(rec + (size_t)pos * 8)     = r0;
    *(float4*)(rec + (size_t)pos * 8 + 4) = r1;
}

// ---------------------------------------------------------------------------
// Weight transpose+cast to bf16 [n][k] for MFMA B-operands.
// ---------------------------------------------------------------------------
__global__ __launch_bounds__(256) void wprep_kernel(
    const float* __restrict__ We1, const float* __restrict__ We2,
    const float* __restrict__ Wv,  const float* __restrict__ Wn1,
    const float* __restrict__ Wn2,
    unsigned short* __restrict__ We1t, unsigned short* __restrict__ We2t,
    unsigned short* __restrict__ Wvt,  unsigned short* __restrict__ Wn1t,
    unsigned short* __restrict__ Wn2t) {
    int l = blockIdx.x, t = threadIdx.x;
    const float* W2 = We2 + (size_t)l * HID * HID;
    unsigned short* T2 = We2t + (size_t)l * HID * HID;
    for (int idx = t; idx < HID * HID; idx += 256) {
        int n = idx >> 6, k = idx & 63;
        T2[n * 64 + k] = f2bf(W2[k * HID + n]);
    }
    const float* Wvl = Wv + (size_t)l * HID * 6;
    unsigned short* Tv = Wvt + (size_t)l * 16 * 64;
    for (int idx = t; idx < 16 * 64; idx += 256) {
        int n = idx >> 6, k = idx & 63;
        Tv[idx] = (n < 6) ? f2bf(Wvl[k * 6 + n]) : (unsigned short)0;
    }
    const float* W1 = We1 + (size_t)l * 257 * 64;
    unsigned short* T1 = We1t + (size_t)l * 128 * 128;
    for (int idx = t; idx < 128 * 128; idx += 256) {
        int n = idx >> 7, k = idx & 127;
        float w = (n < 64) ? W1[(size_t)k * 64 + n] : W1[(size_t)(k + 128) * 64 + (n - 64)];
        T1[n * 128 + k] = f2bf(w);
    }
    const float* Wn1l = Wn1 + (size_t)l * 192 * 64;
    unsigned short* Tn1 = Wn1t + (size_t)l * 64 * 192;
    for (int idx = t; idx < 64 * 192; idx += 256) {
        int n = idx / 192, k = idx - n * 192;
        Tn1[idx] = f2bf(Wn1l[(size_t)k * 64 + n]);
    }
    const float* Wn2l = Wn2 + (size_t)l * 64 * 128;
    unsigned short* Tn2 = Wn2t + (size_t)l * 128 * 64;
    for (int idx = t; idx < 128 * 64; idx += 256) {
        int n = idx >> 6, k = idx & 63;
        Tn2[idx] = f2bf(Wn2l[(size_t)k * 128 + n]);
    }
}

// ---------------------------------------------------------------------------
// node_pre (layer 0 only): [Pa|Pb] = s @ [We1a|We1b] (+be1 on Pa), bf16 out.
// Per-wave, barrier-free: each wave stages + computes its own 16 rows.
// ---------------------------------------------------------------------------
__global__ __launch_bounds__(256) void node_pre_kernel(
    const float* __restrict__ s, const unsigned short* __restrict__ We1t,
    const float* __restrict__ be1,
    unsigned short* __restrict__ Pa, unsigned short* __restrict__ Pb, int N)
{
    __shared__ unsigned short sa[4][16 * 136];
    int t = threadIdx.x;
    int lane = t & 63, w = t >> 6;
    int n0 = blockIdx.x * 64;
    int m0 = w * 16;
    unsigned short* sw = sa[w];
    for (int idx = lane; idx < 512; idx += 64) {
        int rl = idx >> 5, c4 = (idx & 31) << 2;
        int n = n0 + m0 + rl;
        float4 val = make_float4(0.f, 0.f, 0.f, 0.f);
        if (n < N) val = *(const float4*)(s + (size_t)n * SDIM + c4);
        *(uint2*)(sw + rl * 136 + c4) = make_uint2(f2bf2(val.x, val.y), f2bf2(val.z, val.w));
    }
    __builtin_amdgcn_wave_barrier();
    int lm = lane & 15, lq = lane >> 4;

    bf16x8 af[4];
#pragma unroll
    for (int kc = 0; kc < 4; ++kc)
        af[kc] = *(const bf16x8*)(sw + lm * 136 + kc * 32 + lq * 8);

#pragma unroll
    for (int ct = 0; ct < 8; ++ct) {
        int col = ct * 16 + lm;
        f32x4 acc = {0.f, 0.f, 0.f, 0.f};
#pragma unroll
        for (int kc = 0; kc < 4; ++kc) {
            bf16x8 b = *(const bf16x8*)(We1t + (size_t)col * 128 + kc * 32 + lq * 8);
            acc = __builtin_amdgcn_mfma_f32_16x16x32_bf16(af[kc], b, acc, 0, 0, 0);
        }
        float bias = (ct < 4) ? be1[col] : 0.0f;
#pragma unroll
        for (int g = 0; g < 4; ++g) {
            int n = n0 + m0 + lq * 4 + g;
            if (n < N) {
                if (ct < 4) Pa[(size_t)n * HID + col]        = f2bf(acc[g] + bias);
                else        Pb[(size_t)n * HID + (col - 64)] = f2bf(acc[g]);
            }
        }
    }
}

// ---------------------------------------------------------------------------
// Fused edge kernel — per-wave, barrier-free. Each wave owns 16 edges:
// lane reads its own 32B record straight from global (gathers issue at
// instruction ~5), metadata goes to stride-1 SoA LDS (conflict-free),
// all LDS producer->consumer flow is wave-local (in-order LDS pipe).
// ---------------------------------------------------------------------------
__global__ __launch_bounds__(256) void edge_kernel(
    const float* __restrict__ rec,
    const unsigned short* __restrict__ Pa, const unsigned short* __restrict__ Pb,
    const float* __restrict__ wd,
    const unsigned short* __restrict__ We2t, const float* __restrict__ be2,
    const unsigned short* __restrict__ Wvt, const float* __restrict__ bv,
    const float* __restrict__ v,
    float* __restrict__ agg_s, float* __restrict__ agg_v, int E)
{
    __shared__ unsigned short hb[64 * 72];   // h bf16, stride 72 shorts (144B)
    __shared__ float  gl[64 * 8];
    __shared__ float  vb[64 * 12];           // v[src] rows (9 used, pad 12)
    __shared__ int    m_dst[64];
    __shared__ float  m_C[64];
    __shared__ float4 m_r4[64];
    int t = threadIdx.x;
    int e0 = blockIdx.x * 64;
    int lane = t & 63, w = t >> 6;
    int lm = lane & 15, lq = lane >> 4;
    int m0 = w * 16, rm = m0 + lm;
    int ka = lq * 8, kb = 32 + lq * 8;

    // ---- own record from global: issues immediately ----
    int e  = e0 + rm;
    int ec = min(e, E - 1);
    float4 r0 = *(const float4*)(rec + (size_t)ec * 8);
    int srcr = __float_as_int(r0.x);
    int dstr = __float_as_int(r0.y);
    float dv = r0.z;
    float Cr = (e < E) ? r0.w : 0.0f;

    // ---- Pa/Pb gathers: on the critical path, issue ASAP ----
    const unsigned short* pa = Pa + (size_t)dstr * HID;
    const unsigned short* pb = Pb + (size_t)srcr * HID;
    bf16x8 ba0 = *(const bf16x8*)(pa + ka);
    bf16x8 bb0 = *(const bf16x8*)(pb + ka);
    bf16x8 ba1 = *(const bf16x8*)(pa + kb);
    bf16x8 bb1 = *(const bf16x8*)(pb + kb);
    f8 xw = load8(wd + ka), yw = load8(wd + kb);

    // ---- wave-local metadata staging (stride-1 SoA, conflict-free) ----
    if (lq == 0) {
        m_dst[rm] = dstr;
        m_C[rm]   = Cr;
        m_r4[rm]  = *(const float4*)(rec + (size_t)ec * 8 + 4);
    }
    // v[src] row: 4 lanes (lq) cooperate per row, all share the same srcr
    {
        const float* vr = v + (size_t)srcr * 9;
        if (lq < 2) {
            float4_u a = *(const float4_u*)(vr + lq * 4);
            *(float4*)(vb + rm * 12 + lq * 4) = make_float4(a.x, a.y, a.z, a.w);
        } else if (lq == 2) {
            vb[rm * 12 + 8] = vr[8];
        }
    }
    // ---- prefetch Wv^T fragments (A-operand of gates MFMA) ----
    bf16x8 wv0 = *(const bf16x8*)(Wvt + (size_t)lm * 64 + ka);
    bf16x8 wv1 = *(const bf16x8*)(Wvt + (size_t)lm * 64 + kb);

    // ---- phase 1: h1 in MFMA A-layout, registers only ----
    bf16x8 afr0, afr1;
    {
        float fa[8], fb[8], h1[8];
        unpack8(ba0, fa); unpack8(bb0, fb);
#pragma unroll
        for (int j = 0; j < 8; ++j) h1[j] = silu_f(fa[j] + fb[j] + dv * xw.v[j]);
        afr0 = pack8(h1);
        unpack8(ba1, fa); unpack8(bb1, fb);
#pragma unroll
        for (int j = 0; j < 8; ++j) h1[j] = silu_f(fa[j] + fb[j] + dv * yw.v[j]);
        afr1 = pack8(h1);
    }

    // ---- phase 2: h = silu(h1@We2+be2)*C via MFMA -> hb bf16 ----
    __builtin_amdgcn_wave_barrier();
    float cc[4];
#pragma unroll
    for (int g = 0; g < 4; ++g) cc[g] = m_C[m0 + lq * 4 + g];
#pragma unroll
    for (int t4 = 0; t4 < 4; ++t4) {
        int col = t4 * 16 + lm;
        bf16x8 b0 = *(const bf16x8*)(We2t + (size_t)col * 64 + ka);
        bf16x8 b1 = *(const bf16x8*)(We2t + (size_t)col * 64 + kb);
        f32x4 a = {0.f, 0.f, 0.f, 0.f};
        a = __builtin_amdgcn_mfma_f32_16x16x32_bf16(afr0, b0, a, 0, 0, 0);
        a = __builtin_amdgcn_mfma_f32_16x16x32_bf16(afr1, b1, a, 0, 0, 0);
        float bias = be2[col];
#pragma unroll
        for (int g = 0; g < 4; ++g) {
            int er = m0 + lq * 4 + g;
            hb[er * 72 + col] = f2bf(silu_f(a[g] + bias) * cc[g]);
        }
    }
    __builtin_amdgcn_wave_barrier();

    // ---- gates = (Wv^T @ h^T): operand-swapped MFMA, gate-major per lane ----
    {
        bf16x8 hb0 = *(const bf16x8*)(hb + rm * 72 + ka);
        bf16x8 hb1 = *(const bf16x8*)(hb + rm * 72 + kb);
        f32x4 ga = {0.f, 0.f, 0.f, 0.f};
        ga = __builtin_amdgcn_mfma_f32_16x16x32_bf16(wv0, hb0, ga, 0, 0, 0);
        ga = __builtin_amdgcn_mfma_f32_16x16x32_bf16(wv1, hb1, ga, 0, 0, 0);
        int er2 = m0 + lm;
        if (lq == 0) {
            float4_u bb = *(const float4_u*)bv;
            *(float4*)(gl + er2 * 8) =
                make_float4(ga[0] + bb.x, ga[1] + bb.y, ga[2] + bb.z, ga[3] + bb.w);
        } else if (lq == 1) {
            gl[er2 * 8 + 4] = ga[0] + bv[4];
            gl[er2 * 8 + 5] = ga[1] + bv[5];
        }
    }

    // ---- agg_s: segmented column-sum over own 16 rows (dst broadcast reads) ----
    {
        int c = lane;
        float acc = 0.f;
        int cur = m_dst[m0];
#pragma unroll 4
        for (int r = m0; r < m0 + 16; ++r) {
            int dr = m_dst[r];
            if (dr != cur) {
                atomicAdd(&agg_s[(size_t)cur * HID + c], acc);
                acc = 0.f; cur = dr;
            }
            acc += bf2f(hb[r * 72 + c]);
        }
        atomicAdd(&agg_s[(size_t)cur * HID + c], acc);
    }
    __builtin_amdgcn_wave_barrier();

    // ---- agg_v: mv = v[src]*g1 + r*g2, segmented over own 16 rows ----
    if (lane < 36) {
        int seg = lane / 9;
        int c = lane - seg * 9;
        int i = c / 3, j = c - i * 3;
        int r0v = m0 + seg * 4;
        const float* mrf = (const float*)m_r4;
        float acc = 0.f;
        int cur = m_dst[r0v];
#pragma unroll
        for (int r = 0; r < 4; ++r) {
            int rr = r0v + r;
            int dr = m_dst[rr];
            if (dr != cur) {
                atomicAdd(&agg_v[(size_t)cur * 9 + c], acc);
                acc = 0.f; cur = dr;
            }
            if (e0 + rr < E) {
                acc += vb[rr * 12 + c] * gl[rr * 8 + j]
                     + mrf[rr * 4 + i] * gl[rr * 8 + 3 + j];
            }
        }
        atomicAdd(&agg_v[(size_t)cur * 9 + c], acc);
    }
}

// ---------------------------------------------------------------------------
// Fused node kernel — per-wave, barrier-free. Each wave owns 16 rows:
// stages its own s/agg_s slab, runs GEMM1->GEMM2->preGEMM on its quadrant.
// Per-wave LDS slabs keep the sa-alias wave-local (no cross-wave overlap).
// ---------------------------------------------------------------------------
__global__ __launch_bounds__(256) void node_fused_kernel(
    float* __restrict__ s, float* __restrict__ vout,
    float* __restrict__ agg_s, float* __restrict__ agg_v,
    const int* __restrict__ row_start,
    const unsigned short* __restrict__ Wn1t, const float* __restrict__ bn1,
    const unsigned short* __restrict__ Wn2t, const float* __restrict__ bn2,
    const unsigned short* __restrict__ We1tn, const float* __restrict__ be1n,
    unsigned short* __restrict__ Pa, unsigned short* __restrict__ Pb,
    int N, int do_pre)
{
    __shared__ unsigned short xa[4][16 * 200];  // per-wave: [s|agg_s]; alias: s_new (stride 136)
    __shared__ unsigned short ub[64 * 72];
    int t = threadIdx.x;
    int lane = t & 63, w = t >> 6;
    int n0 = blockIdx.x * 64;
    int m0 = w * 16;
    unsigned short* xw = xa[w];

    for (int idx = lane; idx < 512; idx += 64) {
        int rl = idx >> 5, c4 = (idx & 31) << 2;
        int n = n0 + m0 + rl;
        float4 val = make_float4(0.f, 0.f, 0.f, 0.f);
        if (n < N) val = *(const float4*)(s + (size_t)n * SDIM + c4);
        *(uint2*)(xw + rl * 200 + c4) = make_uint2(f2bf2(val.x, val.y), f2bf2(val.z, val.w));
    }
    for (int idx = lane; idx < 256; idx += 64) {
        int rl = idx >> 4, c4 = (idx & 15) << 2;
        int n = n0 + m0 + rl;
        float4 val = make_float4(0.f, 0.f, 0.f, 0.f);
        if (n < N) {
            float* ap = agg_s + (size_t)n * HID + c4;
            val = *(const float4*)ap;
            *(float4*)ap = make_float4(0.f, 0.f, 0.f, 0.f);   // zero for next layer
        }
        *(uint2*)(xw + rl * 200 + 128 + c4) = make_uint2(f2bf2(val.x, val.y), f2bf2(val.z, val.w));
    }
    __builtin_amdgcn_wave_barrier();

    int lm = lane & 15, lq = lane >> 4;

    // ---- GEMM1: u = silu(x @ Wn1 + bn1) ----
    bf16x8 af[6];
#pragma unroll
    for (int kc = 0; kc < 6; ++kc)
        af[kc] = *(const bf16x8*)(xw + lm * 200 + kc * 32 + lq * 8);

#pragma unroll
    for (int ct = 0; ct < 4; ++ct) {
        int col = ct * 16 + lm;
        f32x4 acc = {0.f, 0.f, 0.f, 0.f};
#pragma unroll
        for (int kc = 0; kc < 6; ++kc) {
            bf16x8 b = *(const bf16x8*)(Wn1t + (size_t)col * 192 + kc * 32 + lq * 8);
            acc = __builtin_amdgcn_mfma_f32_16x16x32_bf16(af[kc], b, acc, 0, 0, 0);
        }
        float bias = bn1[col];
#pragma unroll
        for (int g = 0; g < 4; ++g) {
            int er = m0 + lq * 4 + g;
            ub[er * 72 + col] = f2bf(silu_f(acc[g] + bias));
        }
    }
    __builtin_amdgcn_wave_barrier();

    // ---- GEMM2: s_new = s + u @ Wn2 + bn2 ; stash s_new bf16 in wave slab ----
    unsigned short* sa = xw;   // alias (stride 136, wave-local)
    bf16x8 uf[2];
#pragma unroll
    for (int kc = 0; kc < 2; ++kc)
        uf[kc] = *(const bf16x8*)(ub + (m0 + lm) * 72 + kc * 32 + lq * 8);

#pragma unroll
    for (int ct = 0; ct < 8; ++ct) {
        int col = ct * 16 + lm;
        f32x4 acc = {0.f, 0.f, 0.f, 0.f};
#pragma unroll
        for (int kc = 0; kc < 2; ++kc) {
            bf16x8 b = *(const bf16x8*)(Wn2t + (size_t)col * 64 + kc * 32 + lq * 8);
            acc = __builtin_amdgcn_mfma_f32_16x16x32_bf16(uf[kc], b, acc, 0, 0, 0);
        }
        float bias = bn2[col];
#pragma unroll
        for (int g = 0; g < 4; ++g) {
            int erl = lq * 4 + g;
            int n = n0 + m0 + erl;
            if (n < N) {
                float* sp = s + (size_t)n * SDIM + col;
                float sv = *sp + acc[g] + bias;
                *sp = sv;
                sa[erl * 136 + col] = f2bf(sv);
            } else {
                sa[erl * 136 + col] = 0;
            }
        }
    }
    __builtin_amdgcn_wave_barrier();

    // ---- pre-GEMM for next layer: [Pa|Pb] = s_new @ We1(l+1) (bf16 out) ----
    if (do_pre) {
        bf16x8 pf[4];
#pragma unroll
        for (int kc = 0; kc < 4; ++kc)
            pf[kc] = *(const bf16x8*)(sa + lm * 136 + kc * 32 + lq * 8);

#pragma unroll
        for (int ct = 0; ct < 8; ++ct) {
            int col = ct * 16 + lm;
            f32x4 acc = {0.f, 0.f, 0.f, 0.f};
#pragma unroll
            for (int kc = 0; kc < 4; ++kc) {
                bf16x8 b = *(const bf16x8*)(We1tn + (size_t)col * 128 + kc * 32 + lq * 8);
                acc = __builtin_amdgcn_mfma_f32_16x16x32_bf16(pf[kc], b, acc, 0, 0, 0);
            }
            float bias = (ct < 4) ? be1n[col] : 0.0f;
#pragma unroll
            for (int g = 0; g < 4; ++g) {
                int n = n0 + m0 + lq * 4 + g;
                if (n < N) {
                    if (ct < 4) Pa[(size_t)n * HID + col]        = f2bf(acc[g] + bias);
                    else        Pb[(size_t)n * HID + (col - 64)] = f2bf(acc[g]);
                }
            }
        }
    }

    // ---- v += agg_v / max(deg,1) ; zero agg_v for next layer ----
    for (int idx = lane; idx < 144; idx += 64) {
        int rl = idx / 9, c = idx - rl * 9;
        int n2 = n0 + m0 + rl;
        if (n2 < N) {
            float av = agg_v[(size_t)n2 * 9 + c];
            agg_v[(size_t)n2 * 9 + c] = 0.f;
            float dg = fmaxf((float)(row_start[n2 + 1] - row_start[n2]), 1.0f);
            vout[(size_t)n2 * 9 + c] += av / dg;
        }
    }
}

extern "C" void kernel_launch(void* const* d_in, const int* in_sizes, int n_in,
                              void* d_out, int out_size, void* d_ws, size_t ws_size,
                              hipStream_t stream)
{
    const float* s_in  = (const float*)d_in[0];
    const float* v_in  = (const float*)d_in[1];
    const void*  ei    = d_in[2];
    const float* d_vec = (const float*)d_in[3];
    const float* r_vec = (const float*)d_in[4];
    const float* We1 = (const float*)d_in[6];
    const float* be1 = (const float*)d_in[7];
    const float* We2 = (const float*)d_in[8];
    const float* be2 = (const float*)d_in[9];
    const float* Wn1 = (const float*)d_in[10];
    const float* bn1 = (const float*)d_in[11];
    const float* Wn2 = (const float*)d_in[12];
    const float* bn2 = (const float*)d_in[13];
    const float* Wv  = (const float*)d_in[14];
    const float* bv  = (const float*)d_in[15];

    int N = in_sizes[0] / SDIM;
    int E = in_sizes[3];

    float* out_s = (float*)d_out;
    float* out_v = out_s + (size_t)N * SDIM;

    // ------ workspace layout (32B-aligned blocks) ------
    char* wp = (char*)d_ws;
    auto alloc = [&wp](size_t bytes) -> char* {
        char* p = wp;
        wp += (bytes + 31) & ~(size_t)31;
        return p;
    };
    float* rec       = (float*)alloc((size_t)E * 8 * 4);
    unsigned short* Pa = (unsigned short*)alloc((size_t)N * HID * 2);
    unsigned short* Pb = (unsigned short*)alloc((size_t)N * HID * 2);
    float* agg_s     = (float*)alloc((size_t)N * HID * 4);   // contiguous with agg_v
    float* agg_v     = (float*)alloc((size_t)N * 9 * 4);
    int*   deg_i     = (int*)alloc((size_t)N * 4);           // contiguous with cursor
    int*   cursor    = (int*)alloc((size_t)N * 4);
    int*   row_start = (int*)alloc((size_t)(N + 1) * 4);
    int*   part      = (int*)alloc(64 * 4);
    int*   flag      = (int*)alloc(16);
    int*   srcw      = (int*)alloc((size_t)E * 4);
    int*   dstw      = (int*)alloc((size_t)E * 4);
    unsigned short* We2t = (unsigned short*)alloc((size_t)DEPTH * HID * HID * 2);
    unsigned short* Wvt  = (unsigned short*)alloc((size_t)DEPTH * 16 * 64 * 2);
    unsigned short* We1t = (unsigned short*)alloc((size_t)DEPTH * 128 * 128 * 2);
    unsigned short* Wn1t = (unsigned short*)alloc((size_t)DEPTH * 64 * 192 * 2);
    unsigned short* Wn2t = (unsigned short*)alloc((size_t)DEPTH * 128 * 64 * 2);

    hipMemcpyAsync(out_s, s_in, (size_t)N * SDIM * sizeof(float),
                   hipMemcpyDeviceToDevice, stream);
    hipMemcpyAsync(out_v, v_in, (size_t)N * 9 * sizeof(float),
                   hipMemcpyDeviceToDevice, stream);

    // ------ one-time prep ------
    detect_idx_kernel<<<1, 64, 0, stream>>>(ei, N, flag);
    hipMemsetAsync(deg_i, 0, (size_t)N * 2 * sizeof(int), stream);    // deg_i + cursor
    hipMemsetAsync(agg_s, 0, (size_t)N * (HID + 9) * sizeof(float), stream);
    decode_idx_kernel<<<(2 * E + 255) / 256, 256, 0, stream>>>(ei, E, N, flag,
                                                               srcw, dstw, deg_i);
    int B1 = (N + CHUNK - 1) / CHUNK;
    scan1_kernel<<<B1, 256, 0, stream>>>(deg_i, part, N);
    scan2_kernel<<<1, 64, 0, stream>>>(part, row_start, B1, N);
    scan3_kernel<<<B1, 256, 0, stream>>>(deg_i, part, row_start, N);
    scatter_kernel<<<(E + 255) / 256, 256, 0, stream>>>(srcw, dstw, d_vec, r_vec,
                                                        row_start, cursor, rec, E);
    wprep_kernel<<<DEPTH, 256, 0, stream>>>(We1, We2, Wv, Wn1, Wn2,
                                            We1t, We2t, Wvt, Wn1t, Wn2t);

    int nb_n = (N + 63) / 64;
    int nb_e = (E + 63) / 64;
    node_pre_kernel<<<nb_n, 256, 0, stream>>>(out_s, We1t, be1, Pa, Pb, N);
    for (int l = 0; l < DEPTH; ++l) {
        int ln = (l + 1 < DEPTH) ? (l + 1) : 0;
        const float* We1_l = We1 + (size_t)l * 257 * 64;
        const float* be2_l = be2 + (size_t)l * 64;
        const float* bn1_l = bn1 + (size_t)l * 64;
        const float* bn2_l = bn2 + (size_t)l * 128;
        const float* bv_l  = bv  + (size_t)l * 6;
        const float* be1_n = be1 + (size_t)ln * 64;
        const unsigned short* We2t_l = We2t + (size_t)l * HID * HID;
        const unsigned short* Wvt_l  = Wvt  + (size_t)l * 16 * 64;
        const unsigned short* Wn1t_l = Wn1t + (size_t)l * 64 * 192;
        const unsigned short* Wn2t_l = Wn2t + (size_t)l * 128 * 64;
        const unsigned short* We1t_n = We1t + (size_t)ln * 128 * 128;

        edge_kernel<<<nb_e, 256, 0, stream>>>(rec, Pa, Pb,
                                              We1_l + 256 * 64,
                                              We2t_l, be2_l, Wvt_l, bv_l,
                                              out_v, agg_s, agg_v, E);
        node_fused_kernel<<<nb_n, 256, 0, stream>>>(out_s, out_v, agg_s, agg_v,
                                                    row_start,
                                                    Wn1t_l, bn1_l, Wn2t_l, bn2_l,
                                                    We1t_n, be1_n, Pa, Pb,
                                                    N, (l + 1 < DEPTH) ? 1 : 0);
    }
}

// Round 4
// 809.605 us; speedup vs baseline: 1.0167x; 1.0070x over previous
//
#include <hip/hip_runtime.h>
#include <math.h>

#define SDIM 128
#define HID 64
#define DEPTH 4
#define CUTOFF_F 5.0f
#define CHUNK 4096

typedef __attribute__((ext_vector_type(8))) short bf16x8;   // 8 bf16 = 4 VGPRs
typedef __attribute__((ext_vector_type(4))) float f32x4;
typedef float4 __attribute__((aligned(4))) float4_u;        // 4B-aligned float4 load

// fast silu: v_exp + v_rcp
__device__ __forceinline__ float silu_f(float x) {
    float e = __expf(-x);
    return x * __builtin_amdgcn_rcpf(1.0f + e);
}

// Native bf16 convert (RNE) — lowers to v_cvt_pk_bf16_f32 on gfx950.
__device__ __forceinline__ unsigned short f2bf(float x) {
    __bf16 b = (__bf16)x;
    return __builtin_bit_cast(unsigned short, b);
}
__device__ __forceinline__ unsigned int f2bf2(float a, float b) {
    return (unsigned int)f2bf(a) | ((unsigned int)f2bf(b) << 16);
}
__device__ __forceinline__ float bf2f(unsigned short u) {
    return __uint_as_float(((unsigned int)u) << 16);
}

struct f8 { float v[8]; };
__device__ __forceinline__ f8 load8(const float* p) {
    f8 r;
    float4 a = *(const float4*)p;
    float4 b = *(const float4*)(p + 4);
    r.v[0]=a.x; r.v[1]=a.y; r.v[2]=a.z; r.v[3]=a.w;
    r.v[4]=b.x; r.v[5]=b.y; r.v[6]=b.z; r.v[7]=b.w;
    return r;
}
__device__ __forceinline__ bf16x8 pack8(const float* h) {
    bf16x8 o;
#pragma unroll
    for (int j = 0; j < 8; ++j) o[j] = (short)f2bf(h[j]);
    return o;
}
__device__ __forceinline__ void unpack8(bf16x8 b, float* o) {
#pragma unroll
    for (int j = 0; j < 8; ++j)
        o[j] = __uint_as_float(((unsigned int)(unsigned short)b[j]) << 16);
}

// ---------------------------------------------------------------------------
// Index decode + degree histogram.
// ---------------------------------------------------------------------------
__global__ void detect_idx_kernel(const void* ei, int N, int* flag) {
    int lane = threadIdx.x;   // 64 lanes
    const long long* p64 = (const long long*)ei;
    long long v = p64[lane];
    bool ok = (v >= 0 && v < (long long)N);
    unsigned long long m = __ballot(ok);
    if (lane == 0) *flag = (m == ~0ull) ? 1 : 0;
}

__global__ void decode_idx_kernel(const void* ei, int E, int N, const int* flag,
                                  int* __restrict__ srcw, int* __restrict__ dstw,
                                  int* __restrict__ deg_i) {
    int i = blockIdx.x * blockDim.x + threadIdx.x;
    if (i >= 2 * E) return;
    int v;
    if (*flag) v = (int)((const long long*)ei)[i];
    else       v = ((const int*)ei)[i];
    v = min(max(v, 0), N - 1);
    if (i < E) {
        srcw[i] = v;
    } else {
        dstw[i - E] = v;
        atomicAdd(&deg_i[v], 1);
    }
}

// ---------------------------------------------------------------------------
// 3-phase parallel exclusive scan: deg_i -> row_start[0..N]
// ---------------------------------------------------------------------------
__global__ __launch_bounds__(256) void scan1_kernel(const int* __restrict__ deg_i,
                                                    int* __restrict__ part, int N) {
    __shared__ int wsum[4];
    int b = blockIdx.x, t = threadIdx.x;
    int base = b * CHUNK;
    int sum = 0;
    for (int i = t; i < CHUNK; i += 256) {
        int idx = base + i;
        sum += (idx < N) ? deg_i[idx] : 0;
    }
#pragma unroll
    for (int off = 32; off; off >>= 1) sum += __shfl_down(sum, off, 64);
    if ((t & 63) == 0) wsum[t >> 6] = sum;
    __syncthreads();
    if (t == 0) part[b] = wsum[0] + wsum[1] + wsum[2] + wsum[3];
}

__global__ void scan2_kernel(int* __restrict__ part, int* __restrict__ row_start,
                             int B1, int N) {
    int t = threadIdx.x;   // 64 threads
    int v = (t < B1) ? part[t] : 0;
    int incl = v;
#pragma unroll
    for (int off = 1; off < 64; off <<= 1) {
        int x = __shfl_up(incl, off, 64);
        if (t >= off) incl += x;
    }
    if (t < B1) part[t] = incl - v;      // exclusive
    if (t == 63) row_start[N] = incl;    // grand total
}

__global__ __launch_bounds__(256) void scan3_kernel(const int* __restrict__ deg_i,
                                                    const int* __restrict__ part,
                                                    int* __restrict__ row_start, int N) {
    __shared__ int wsum[4];
    __shared__ int carry_s;
    int b = blockIdx.x, t = threadIdx.x;
    int lane = t & 63, w = t >> 6;
    if (t == 0) carry_s = part[b];
    __syncthreads();
    int base0 = b * CHUNK;
    for (int base = base0; base < base0 + CHUNK; base += 256) {
        int i = base + t;
        int v = (i < N) ? deg_i[i] : 0;
        int incl = v;
#pragma unroll
        for (int off = 1; off < 64; off <<= 1) {
            int x = __shfl_up(incl, off, 64);
            if (lane >= off) incl += x;
        }
        if (lane == 63) wsum[w] = incl;
        __syncthreads();
        int wpre = 0;
#pragma unroll
        for (int k = 0; k < 4; ++k) if (k < w) wpre += wsum[k];
        int total = wsum[0] + wsum[1] + wsum[2] + wsum[3];
        int carry = carry_s;
        if (i < N) row_start[i] = carry + wpre + incl - v;
        __syncthreads();
        if (t == 0) carry_s = carry + total;
        __syncthreads();
    }
}

// ---------------------------------------------------------------------------
// Scatter: dst-sorted permutation; one packed 32B record per edge.
// ---------------------------------------------------------------------------
__global__ void scatter_kernel(const int* __restrict__ srcw, const int* __restrict__ dstw,
                               const float* __restrict__ dvec, const float* __restrict__ rvec,
                               const int* __restrict__ row_start, int* __restrict__ cursor,
                               float* __restrict__ rec, int E) {
    int e = blockIdx.x * blockDim.x + threadIdx.x;
    if (e >= E) return;
    int dd = dstw[e];
    int ofs = atomicAdd(&cursor[dd], 1);
    int pos = row_start[dd] + ofs;
    float dv = dvec[e];
    float c = 0.5f * (cosf(3.14159265358979323846f * dv * (1.0f / CUTOFF_F)) + 1.0f);
    c = (dv < CUTOFF_F) ? c : 0.0f;
    float4 r0 = make_float4(__int_as_float(srcw[e]), __int_as_float(dd), dv, c);
    float4 r1 = make_float4(rvec[(size_t)e * 3 + 0], rvec[(size_t)e * 3 + 1],
                            rvec[(size_t)e * 3 + 2], 0.0f);
    *(float4*)(rec + (size_t)pos * 8)     = r0;
    *(float4*)(rec + (size_t)pos * 8 + 4) = r1;
}

// ---------------------------------------------------------------------------
// Weight transpose+cast to bf16 [n][k] for MFMA B-operands.
// ---------------------------------------------------------------------------
__global__ __launch_bounds__(256) void wprep_kernel(
    const float* __restrict__ We1, const float* __restrict__ We2,
    const float* __restrict__ Wv,  const float* __restrict__ Wn1,
    const float* __restrict__ Wn2,
    unsigned short* __restrict__ We1t, unsigned short* __restrict__ We2t,
    unsigned short* __restrict__ Wvt,  unsigned short* __restrict__ Wn1t,
    unsigned short* __restrict__ Wn2t) {
    int l = blockIdx.x, t = threadIdx.x;
    const float* W2 = We2 + (size_t)l * HID * HID;
    unsigned short* T2 = We2t + (size_t)l * HID * HID;
    for (int idx = t; idx < HID * HID; idx += 256) {
        int n = idx >> 6, k = idx & 63;
        T2[n * 64 + k] = f2bf(W2[k * HID + n]);
    }
    const float* Wvl = Wv + (size_t)l * HID * 6;
    unsigned short* Tv = Wvt + (size_t)l * 16 * 64;
    for (int idx = t; idx < 16 * 64; idx += 256) {
        int n = idx >> 6, k = idx & 63;
        Tv[idx] = (n < 6) ? f2bf(Wvl[k * 6 + n]) : (unsigned short)0;
    }
    const float* W1 = We1 + (size_t)l * 257 * 64;
    unsigned short* T1 = We1t + (size_t)l * 128 * 128;
    for (int idx = t; idx < 128 * 128; idx += 256) {
        int n = idx >> 7, k = idx & 127;
        float w = (n < 64) ? W1[(size_t)k * 64 + n] : W1[(size_t)(k + 128) * 64 + (n - 64)];
        T1[n * 128 + k] = f2bf(w);
    }
    const float* Wn1l = Wn1 + (size_t)l * 192 * 64;
    unsigned short* Tn1 = Wn1t + (size_t)l * 64 * 192;
    for (int idx = t; idx < 64 * 192; idx += 256) {
        int n = idx / 192, k = idx - n * 192;
        Tn1[idx] = f2bf(Wn1l[(size_t)k * 64 + n]);
    }
    const float* Wn2l = Wn2 + (size_t)l * 64 * 128;
    unsigned short* Tn2 = Wn2t + (size_t)l * 128 * 64;
    for (int idx = t; idx < 128 * 64; idx += 256) {
        int n = idx >> 6, k = idx & 63;
        Tn2[idx] = f2bf(Wn2l[(size_t)k * 128 + n]);
    }
}

// ---------------------------------------------------------------------------
// node_pre (layer 0 only): [Pa|Pb] = s @ [We1a|We1b] (+be1 on Pa), bf16 out.
// 64-thread blocks, 16 rows each (grid N/16 for load balance).
// ---------------------------------------------------------------------------
__global__ __launch_bounds__(64) void node_pre_kernel(
    const float* __restrict__ s, const unsigned short* __restrict__ We1t,
    const float* __restrict__ be1,
    unsigned short* __restrict__ Pa, unsigned short* __restrict__ Pb, int N)
{
    __shared__ unsigned short sa[16 * 136];
    int lane = threadIdx.x;
    int n0 = blockIdx.x * 16;
    for (int idx = lane; idx < 512; idx += 64) {
        int rl = idx >> 5, c4 = (idx & 31) << 2;
        int n = n0 + rl;
        float4 val = make_float4(0.f, 0.f, 0.f, 0.f);
        if (n < N) val = *(const float4*)(s + (size_t)n * SDIM + c4);
        *(uint2*)(sa + rl * 136 + c4) = make_uint2(f2bf2(val.x, val.y), f2bf2(val.z, val.w));
    }
    __builtin_amdgcn_wave_barrier();
    int lm = lane & 15, lq = lane >> 4;

    bf16x8 af[4];
#pragma unroll
    for (int kc = 0; kc < 4; ++kc)
        af[kc] = *(const bf16x8*)(sa + lm * 136 + kc * 32 + lq * 8);

#pragma unroll
    for (int ct = 0; ct < 8; ++ct) {
        int col = ct * 16 + lm;
        f32x4 acc = {0.f, 0.f, 0.f, 0.f};
#pragma unroll
        for (int kc = 0; kc < 4; ++kc) {
            bf16x8 b = *(const bf16x8*)(We1t + (size_t)col * 128 + kc * 32 + lq * 8);
            acc = __builtin_amdgcn_mfma_f32_16x16x32_bf16(af[kc], b, acc, 0, 0, 0);
        }
        float bias = (ct < 4) ? be1[col] : 0.0f;
#pragma unroll
        for (int g = 0; g < 4; ++g) {
            int n = n0 + lq * 4 + g;
            if (n < N) {
                if (ct < 4) Pa[(size_t)n * HID + col]        = f2bf(acc[g] + bias);
                else        Pb[(size_t)n * HID + (col - 64)] = f2bf(acc[g]);
            }
        }
    }
}

// ---------------------------------------------------------------------------
// Edge tile issue: decode record, launch Pa/Pb gathers, stage v row + meta
// into the given double-buffer half. All wave-local.
// ---------------------------------------------------------------------------
__device__ __forceinline__ void issue_tile(
    float4 r0v, bool e_ok, const float* r4p,
    int rm, int lq, int ka, int kb,
    const unsigned short* __restrict__ Pa, const unsigned short* __restrict__ Pb,
    const float* __restrict__ v,
    bf16x8& ba0, bf16x8& bb0, bf16x8& ba1, bf16x8& bb1, float& dv_out,
    int* m_dst, float* m_C, float4* m_r4, float* vb)
{
    int srcr = __float_as_int(r0v.x);
    int dstr = __float_as_int(r0v.y);
    dv_out = r0v.z;
    float Cr = e_ok ? r0v.w : 0.0f;
    const unsigned short* pa = Pa + (size_t)dstr * HID;
    const unsigned short* pb = Pb + (size_t)srcr * HID;
    ba0 = *(const bf16x8*)(pa + ka);
    bb0 = *(const bf16x8*)(pb + ka);
    ba1 = *(const bf16x8*)(pa + kb);
    bb1 = *(const bf16x8*)(pb + kb);
    if (lq == 0) {
        m_dst[rm] = dstr;
        m_C[rm]   = Cr;
        m_r4[rm]  = *(const float4*)r4p;
    }
    const float* vr = v + (size_t)srcr * 9;
    if (lq < 2) {
        float4_u a = *(const float4_u*)(vr + lq * 4);
        *(float4*)(vb + rm * 12 + lq * 4) = make_float4(a.x, a.y, a.z, a.w);
    } else if (lq == 2) {
        vb[rm * 12 + 8] = vr[8];
    }
}

// ---------------------------------------------------------------------------
// Fused edge kernel — persistent blocks, software-pipelined over ~7 tiles.
// Per iteration: prefetch next rec early; after phase2, issue next tile's
// Pa/Pb gathers + v/meta staging (double-buffered) so gather latency hides
// under gates + segmented reductions of the current tile. Loop-invariant
// weights (wd, Wv^T, bv) hoisted out of the tile loop. All wave-local.
// ---------------------------------------------------------------------------
__global__ __launch_bounds__(256) void edge_kernel(
    const float* __restrict__ rec,
    const unsigned short* __restrict__ Pa, const unsigned short* __restrict__ Pb,
    const float* __restrict__ wd,
    const unsigned short* __restrict__ We2t, const float* __restrict__ be2,
    const unsigned short* __restrict__ Wvt, const float* __restrict__ bv,
    const float* __restrict__ v,
    float* __restrict__ agg_s, float* __restrict__ agg_v,
    int E, int ntiles, int tpb)
{
    __shared__ unsigned short hb[64 * 72];   // h bf16, stride 72 shorts (144B)
    __shared__ float  gl[64 * 8];
    __shared__ float  vb2[2][64 * 12];       // v[src] rows (9 used, pad 12)
    __shared__ int    m_dst2[2][64];
    __shared__ float  m_C2[2][64];
    __shared__ float4 m_r42[2][64];

    int t = threadIdx.x;
    int lane = t & 63, w = t >> 6;
    int lm = lane & 15, lq = lane >> 4;
    int m0 = w * 16, rm = m0 + lm;
    int ka = lq * 8, kb = 32 + lq * 8;

    int t0 = blockIdx.x * tpb;
    int t1 = min(t0 + tpb, ntiles);
    if (t0 >= t1) return;

    // ---- loop-invariant weights, loaded once per wave ----
    f8 xw = load8(wd + ka), yw = load8(wd + kb);
    bf16x8 wv0 = *(const bf16x8*)(Wvt + (size_t)lm * 64 + ka);
    bf16x8 wv1 = *(const bf16x8*)(Wvt + (size_t)lm * 64 + kb);
    float4_u bvv = *(const float4_u*)bv;
    float bv4 = bv[4], bv5 = bv[5];

    // ---- prologue: tile t0 record + gathers + staging ----
    bf16x8 ba0, bb0, ba1, bb1;
    float dv;
    {
        int e  = t0 * 64 + rm;
        int ec = min(e, E - 1);
        float4 r0 = *(const float4*)(rec + (size_t)ec * 8);
        int par0 = t0 & 1;
        issue_tile(r0, e < E, rec + (size_t)ec * 8 + 4, rm, lq, ka, kb, Pa, Pb, v,
                   ba0, bb0, ba1, bb1, dv,
                   m_dst2[par0], m_C2[par0], m_r42[par0], vb2[par0]);
    }

    for (int itl = t0; itl < t1; ++itl) {
        int par = itl & 1, npar = par ^ 1;
        bool hasnext = (itl + 1 < t1);
        int en  = (itl + 1) * 64 + rm;
        int ecn = min(en, E - 1);
        float4 r0n;
        if (hasnext) r0n = *(const float4*)(rec + (size_t)ecn * 8);  // prefetch

        // ---- phase 1: h1 in MFMA A-layout, registers only ----
        bf16x8 afr0, afr1;
        {
            float fa[8], fb[8], h1[8];
            unpack8(ba0, fa); unpack8(bb0, fb);
#pragma unroll
            for (int j = 0; j < 8; ++j) h1[j] = silu_f(fa[j] + fb[j] + dv * xw.v[j]);
            afr0 = pack8(h1);
            unpack8(ba1, fa); unpack8(bb1, fb);
#pragma unroll
            for (int j = 0; j < 8; ++j) h1[j] = silu_f(fa[j] + fb[j] + dv * yw.v[j]);
            afr1 = pack8(h1);
        }

        // ---- phase 2: h = silu(h1@We2+be2)*C via MFMA -> hb bf16 ----
        float cc[4];
#pragma unroll
        for (int g = 0; g < 4; ++g) cc[g] = m_C2[par][m0 + lq * 4 + g];
#pragma unroll
        for (int t4 = 0; t4 < 4; ++t4) {
            int col = t4 * 16 + lm;
            bf16x8 b0 = *(const bf16x8*)(We2t + (size_t)col * 64 + ka);
            bf16x8 b1 = *(const bf16x8*)(We2t + (size_t)col * 64 + kb);
            f32x4 a = {0.f, 0.f, 0.f, 0.f};
            a = __builtin_amdgcn_mfma_f32_16x16x32_bf16(afr0, b0, a, 0, 0, 0);
            a = __builtin_amdgcn_mfma_f32_16x16x32_bf16(afr1, b1, a, 0, 0, 0);
            float bias = be2[col];
#pragma unroll
            for (int g = 0; g < 4; ++g) {
                int er = m0 + lq * 4 + g;
                hb[er * 72 + col] = f2bf(silu_f(a[g] + bias) * cc[g]);
            }
        }
        __builtin_amdgcn_wave_barrier();

        // ---- gates = (Wv^T @ h^T): operand-swapped MFMA, gate-major per lane ----
        {
            bf16x8 hb0 = *(const bf16x8*)(hb + rm * 72 + ka);
            bf16x8 hb1 = *(const bf16x8*)(hb + rm * 72 + kb);
            f32x4 ga = {0.f, 0.f, 0.f, 0.f};
            ga = __builtin_amdgcn_mfma_f32_16x16x32_bf16(wv0, hb0, ga, 0, 0, 0);
            ga = __builtin_amdgcn_mfma_f32_16x16x32_bf16(wv1, hb1, ga, 0, 0, 0);
            int er2 = m0 + lm;
            if (lq == 0) {
                *(float4*)(gl + er2 * 8) =
                    make_float4(ga[0] + bvv.x, ga[1] + bvv.y, ga[2] + bvv.z, ga[3] + bvv.w);
            } else if (lq == 1) {
                gl[er2 * 8 + 4] = ga[0] + bv4;
                gl[er2 * 8 + 5] = ga[1] + bv5;
            }
        }

        // ---- issue next tile: gathers into frag regs, staging into npar buffers.
        //      These fly under the reductions below. ----
        if (hasnext) {
            issue_tile(r0n, en < E, rec + (size_t)ecn * 8 + 4, rm, lq, ka, kb, Pa, Pb, v,
                       ba0, bb0, ba1, bb1, dv,
                       m_dst2[npar], m_C2[npar], m_r42[npar], vb2[npar]);
        }

        // ---- agg_s: segmented column-sum over own 16 rows ----
        {
            int c = lane;
            const int* md = m_dst2[par];
            float acc = 0.f;
            int cur = md[m0];
#pragma unroll 4
            for (int r = m0; r < m0 + 16; ++r) {
                int dr = md[r];
                if (dr != cur) {
                    atomicAdd(&agg_s[(size_t)cur * HID + c], acc);
                    acc = 0.f; cur = dr;
                }
                acc += bf2f(hb[r * 72 + c]);
            }
            atomicAdd(&agg_s[(size_t)cur * HID + c], acc);
        }
        __builtin_amdgcn_wave_barrier();

        // ---- agg_v: mv = v[src]*g1 + r*g2, segmented over own 16 rows ----
        if (lane < 36) {
            int seg = lane / 9;
            int c = lane - seg * 9;
            int i = c / 3, j = c - i * 3;
            int r0v = m0 + seg * 4;
            const float* mrf = (const float*)m_r42[par];
            const float* vbp = vb2[par];
            const int* md = m_dst2[par];
            float acc = 0.f;
            int cur = md[r0v];
#pragma unroll
            for (int r = 0; r < 4; ++r) {
                int rr = r0v + r;
                int dr = md[rr];
                if (dr != cur) {
                    atomicAdd(&agg_v[(size_t)cur * 9 + c], acc);
                    acc = 0.f; cur = dr;
                }
                if (itl * 64 + rr < E) {
                    acc += vbp[rr * 12 + c] * gl[rr * 8 + j]
                         + mrf[rr * 4 + i] * gl[rr * 8 + 3 + j];
                }
            }
            atomicAdd(&agg_v[(size_t)cur * 9 + c], acc);
        }
        __builtin_amdgcn_wave_barrier();
    }
}

// ---------------------------------------------------------------------------
// Fused node kernel — 64-thread blocks, 16 rows each (grid N/16: fixes the
// 3-blocks/CU quantization imbalance of 64-row blocks). v-update first so
// its independent loads issue early; GEMM2's s re-reads hoisted into regs.
// ---------------------------------------------------------------------------
__global__ __launch_bounds__(64) void node_fused_kernel(
    float* __restrict__ s, float* __restrict__ vout,
    float* __restrict__ agg_s, float* __restrict__ agg_v,
    const int* __restrict__ row_start,
    const unsigned short* __restrict__ Wn1t, const float* __restrict__ bn1,
    const unsigned short* __restrict__ Wn2t, const float* __restrict__ bn2,
    const unsigned short* __restrict__ We1tn, const float* __restrict__ be1n,
    unsigned short* __restrict__ Pa, unsigned short* __restrict__ Pb,
    int N, int do_pre)
{
    __shared__ unsigned short xa[16 * 200];  // phase A: [s|agg_s]; alias: s_new (stride 136)
    __shared__ unsigned short ub[16 * 72];
    int lane = threadIdx.x;
    int n0 = blockIdx.x * 16;

    // ---- v += agg_v / max(deg,1) ; zero agg_v (independent: issue first) ----
    for (int idx = lane; idx < 144; idx += 64) {
        int rl = idx / 9, c = idx - rl * 9;
        int n2 = n0 + rl;
        if (n2 < N) {
            float av = agg_v[(size_t)n2 * 9 + c];
            agg_v[(size_t)n2 * 9 + c] = 0.f;
            float dg = fmaxf((float)(row_start[n2 + 1] - row_start[n2]), 1.0f);
            vout[(size_t)n2 * 9 + c] += av / dg;
        }
    }

    // ---- stage [s | agg_s] as bf16 (zero agg_s after read) ----
    for (int idx = lane; idx < 512; idx += 64) {
        int rl = idx >> 5, c4 = (idx & 31) << 2;
        int n = n0 + rl;
        float4 val = make_float4(0.f, 0.f, 0.f, 0.f);
        if (n < N) val = *(const float4*)(s + (size_t)n * SDIM + c4);
        *(uint2*)(xa + rl * 200 + c4) = make_uint2(f2bf2(val.x, val.y), f2bf2(val.z, val.w));
    }
    for (int idx = lane; idx < 256; idx += 64) {
        int rl = idx >> 4, c4 = (idx & 15) << 2;
        int n = n0 + rl;
        float4 val = make_float4(0.f, 0.f, 0.f, 0.f);
        if (n < N) {
            float* ap = agg_s + (size_t)n * HID + c4;
            val = *(const float4*)ap;
            *(float4*)ap = make_float4(0.f, 0.f, 0.f, 0.f);   // zero for next layer
        }
        *(uint2*)(xa + rl * 200 + 128 + c4) = make_uint2(f2bf2(val.x, val.y), f2bf2(val.z, val.w));
    }
    __builtin_amdgcn_wave_barrier();

    int lm = lane & 15, lq = lane >> 4;

    // ---- GEMM1: u = silu(x @ Wn1 + bn1) ----
    bf16x8 af[6];
#pragma unroll
    for (int kc = 0; kc < 6; ++kc)
        af[kc] = *(const bf16x8*)(xa + lm * 200 + kc * 32 + lq * 8);

#pragma unroll
    for (int ct = 0; ct < 4; ++ct) {
        int col = ct * 16 + lm;
        f32x4 acc = {0.f, 0.f, 0.f, 0.f};
#pragma unroll
        for (int kc = 0; kc < 6; ++kc) {
            bf16x8 b = *(const bf16x8*)(Wn1t + (size_t)col * 192 + kc * 32 + lq * 8);
            acc = __builtin_amdgcn_mfma_f32_16x16x32_bf16(af[kc], b, acc, 0, 0, 0);
        }
        float bias = bn1[col];
#pragma unroll
        for (int g = 0; g < 4; ++g) {
            int er = lq * 4 + g;
            ub[er * 72 + col] = f2bf(silu_f(acc[g] + bias));
        }
    }
    __builtin_amdgcn_wave_barrier();

    // ---- GEMM2: s_new = s + u @ Wn2 + bn2 ; stash s_new bf16 in LDS ----
    unsigned short* sa = xa;   // alias (stride 136)
    bf16x8 uf[2];
#pragma unroll
    for (int kc = 0; kc < 2; ++kc)
        uf[kc] = *(const bf16x8*)(ub + lm * 72 + kc * 32 + lq * 8);

    // hoist the 32 s re-reads ahead of the MFMAs
    float sld[32];
#pragma unroll
    for (int ct = 0; ct < 8; ++ct) {
#pragma unroll
        for (int g = 0; g < 4; ++g) {
            int n = n0 + lq * 4 + g;
            sld[ct * 4 + g] = (n < N) ? s[(size_t)n * SDIM + ct * 16 + lm] : 0.0f;
        }
    }

#pragma unroll
    for (int ct = 0; ct < 8; ++ct) {
        int col = ct * 16 + lm;
        f32x4 acc = {0.f, 0.f, 0.f, 0.f};
#pragma unroll
        for (int kc = 0; kc < 2; ++kc) {
            bf16x8 b = *(const bf16x8*)(Wn2t + (size_t)col * 64 + kc * 32 + lq * 8);
            acc = __builtin_amdgcn_mfma_f32_16x16x32_bf16(uf[kc], b, acc, 0, 0, 0);
        }
        float bias = bn2[col];
#pragma unroll
        for (int g = 0; g < 4; ++g) {
            int erl = lq * 4 + g;
            int n = n0 + erl;
            if (n < N) {
                float sv = sld[ct * 4 + g] + acc[g] + bias;
                s[(size_t)n * SDIM + col] = sv;
                sa[erl * 136 + col] = f2bf(sv);
            } else {
                sa[erl * 136 + col] = 0;
            }
        }
    }
    __builtin_amdgcn_wave_barrier();

    // ---- pre-GEMM for next layer: [Pa|Pb] = s_new @ We1(l+1) (bf16 out) ----
    if (do_pre) {
        bf16x8 pf[4];
#pragma unroll
        for (int kc = 0; kc < 4; ++kc)
            pf[kc] = *(const bf16x8*)(sa + lm * 136 + kc * 32 + lq * 8);

#pragma unroll
        for (int ct = 0; ct < 8; ++ct) {
            int col = ct * 16 + lm;
            f32x4 acc = {0.f, 0.f, 0.f, 0.f};
#pragma unroll
            for (int kc = 0; kc < 4; ++kc) {
                bf16x8 b = *(const bf16x8*)(We1tn + (size_t)col * 128 + kc * 32 + lq * 8);
                acc = __builtin_amdgcn_mfma_f32_16x16x32_bf16(pf[kc], b, acc, 0, 0, 0);
            }
            float bias = (ct < 4) ? be1n[col] : 0.0f;
#pragma unroll
            for (int g = 0; g < 4; ++g) {
                int n = n0 + lq * 4 + g;
                if (n < N) {
                    if (ct < 4) Pa[(size_t)n * HID + col]        = f2bf(acc[g] + bias);
                    else        Pb[(size_t)n * HID + (col - 64)] = f2bf(acc[g]);
                }
            }
        }
    }
}

extern "C" void kernel_launch(void* const* d_in, const int* in_sizes, int n_in,
                              void* d_out, int out_size, void* d_ws, size_t ws_size,
                              hipStream_t stream)
{
    const float* s_in  = (const float*)d_in[0];
    const float* v_in  = (const float*)d_in[1];
    const void*  ei    = d_in[2];
    const float* d_vec = (const float*)d_in[3];
    const float* r_vec = (const float*)d_in[4];
    const float* We1 = (const float*)d_in[6];
    const float* be1 = (const float*)d_in[7];
    const float* We2 = (const float*)d_in[8];
    const float* be2 = (const float*)d_in[9];
    const float* Wn1 = (const float*)d_in[10];
    const float* bn1 = (const float*)d_in[11];
    const float* Wn2 = (const float*)d_in[12];
    const float* bn2 = (const float*)d_in[13];
    const float* Wv  = (const float*)d_in[14];
    const float* bv  = (const float*)d_in[15];

    int N = in_sizes[0] / SDIM;
    int E = in_sizes[3];

    float* out_s = (float*)d_out;
    float* out_v = out_s + (size_t)N * SDIM;

    // ------ workspace layout (32B-aligned blocks) ------
    char* wp = (char*)d_ws;
    auto alloc = [&wp](size_t bytes) -> char* {
        char* p = wp;
        wp += (bytes + 31) & ~(size_t)31;
        return p;
    };
    float* rec       = (float*)alloc((size_t)E * 8 * 4);
    unsigned short* Pa = (unsigned short*)alloc((size_t)N * HID * 2);
    unsigned short* Pb = (unsigned short*)alloc((size_t)N * HID * 2);
    float* agg_s     = (float*)alloc((size_t)N * HID * 4);   // contiguous with agg_v
    float* agg_v     = (float*)alloc((size_t)N * 9 * 4);
    int*   deg_i     = (int*)alloc((size_t)N * 4);           // contiguous with cursor
    int*   cursor    = (int*)alloc((size_t)N * 4);
    int*   row_start = (int*)alloc((size_t)(N + 1) * 4);
    int*   part      = (int*)alloc(64 * 4);
    int*   flag      = (int*)alloc(16);
    int*   srcw      = (int*)alloc((size_t)E * 4);
    int*   dstw      = (int*)alloc((size_t)E * 4);
    unsigned short* We2t = (unsigned short*)alloc((size_t)DEPTH * HID * HID * 2);
    unsigned short* Wvt  = (unsigned short*)alloc((size_t)DEPTH * 16 * 64 * 2);
    unsigned short* We1t = (unsigned short*)alloc((size_t)DEPTH * 128 * 128 * 2);
    unsigned short* Wn1t = (unsigned short*)alloc((size_t)DEPTH * 64 * 192 * 2);
    unsigned short* Wn2t = (unsigned short*)alloc((size_t)DEPTH * 128 * 64 * 2);

    hipMemcpyAsync(out_s, s_in, (size_t)N * SDIM * sizeof(float),
                   hipMemcpyDeviceToDevice, stream);
    hipMemcpyAsync(out_v, v_in, (size_t)N * 9 * sizeof(float),
                   hipMemcpyDeviceToDevice, stream);

    // ------ one-time prep ------
    detect_idx_kernel<<<1, 64, 0, stream>>>(ei, N, flag);
    hipMemsetAsync(deg_i, 0, (size_t)N * 2 * sizeof(int), stream);    // deg_i + cursor
    hipMemsetAsync(agg_s, 0, (size_t)N * (HID + 9) * sizeof(float), stream);
    decode_idx_kernel<<<(2 * E + 255) / 256, 256, 0, stream>>>(ei, E, N, flag,
                                                               srcw, dstw, deg_i);
    int B1 = (N + CHUNK - 1) / CHUNK;
    scan1_kernel<<<B1, 256, 0, stream>>>(deg_i, part, N);
    scan2_kernel<<<1, 64, 0, stream>>>(part, row_start, B1, N);
    scan3_kernel<<<B1, 256, 0, stream>>>(deg_i, part, row_start, N);
    scatter_kernel<<<(E + 255) / 256, 256, 0, stream>>>(srcw, dstw, d_vec, r_vec,
                                                        row_start, cursor, rec, E);
    wprep_kernel<<<DEPTH, 256, 0, stream>>>(We1, We2, Wv, Wn1, Wn2,
                                            We1t, We2t, Wvt, Wn1t, Wn2t);

    int nb_n = (N + 15) / 16;
    int ntiles = (E + 63) / 64;
    int tpb = (ntiles + 2047) / 2048;              // tiles per block (~7)
    int nb_e = (ntiles + tpb - 1) / tpb;           // ~1786 persistent blocks

    node_pre_kernel<<<nb_n, 64, 0, stream>>>(out_s, We1t, be1, Pa, Pb, N);
    for (int l = 0; l < DEPTH; ++l) {
        int ln = (l + 1 < DEPTH) ? (l + 1) : 0;
        const float* We1_l = We1 + (size_t)l * 257 * 64;
        const float* be2_l = be2 + (size_t)l * 64;
        const float* bn1_l = bn1 + (size_t)l * 64;
        const float* bn2_l = bn2 + (size_t)l * 128;
        const float* bv_l  = bv  + (size_t)l * 6;
        const float* be1_n = be1 + (size_t)ln * 64;
        const unsigned short* We2t_l = We2t + (size_t)l * HID * HID;
        const unsigned short* Wvt_l  = Wvt  + (size_t)l * 16 * 64;
        const unsigned short* Wn1t_l = Wn1t + (size_t)l * 64 * 192;
        const unsigned short* Wn2t_l = Wn2t + (size_t)l * 128 * 64;
        const unsigned short* We1t_n = We1t + (size_t)ln * 128 * 128;

        edge_kernel<<<nb_e, 256, 0, stream>>>(rec, Pa, Pb,
                                              We1_l + 256 * 64,
                                              We2t_l, be2_l, Wvt_l, bv_l,
                                              out_v, agg_s, agg_v,
                                              E, ntiles, tpb);
        node_fused_kernel<<<nb_n, 64, 0, stream>>>(out_s, out_v, agg_s, agg_v,
                                                   row_start,
                                                   Wn1t_l, bn1_l, Wn2t_l, bn2_l,
                                                   We1t_n, be1_n, Pa, Pb,
                                                   N, (l + 1 < DEPTH) ? 1 : 0);
    }
}

// Round 5
// 789.689 us; speedup vs baseline: 1.0423x; 1.0252x over previous
//
#include <hip/hip_runtime.h>
#include <math.h>

#define SDIM 128
#define HID 64
#define DEPTH 4
#define CUTOFF_F 5.0f
#define CHUNK 4096

typedef __attribute__((ext_vector_type(8))) short bf16x8;   // 8 bf16 = 4 VGPRs
typedef __attribute__((ext_vector_type(4))) float f32x4;
typedef float4 __attribute__((aligned(4))) float4_u;        // 4B-aligned float4 load

// fast silu: v_exp + v_rcp
__device__ __forceinline__ float silu_f(float x) {
    float e = __expf(-x);
    return x * __builtin_amdgcn_rcpf(1.0f + e);
}

// Native bf16 convert (RNE) — lowers to v_cvt_pk_bf16_f32 on gfx950.
__device__ __forceinline__ unsigned short f2bf(float x) {
    __bf16 b = (__bf16)x;
    return __builtin_bit_cast(unsigned short, b);
}
__device__ __forceinline__ unsigned int f2bf2(float a, float b) {
    return (unsigned int)f2bf(a) | ((unsigned int)f2bf(b) << 16);
}
__device__ __forceinline__ float bf2f(unsigned short u) {
    return __uint_as_float(((unsigned int)u) << 16);
}

struct f8 { float v[8]; };
__device__ __forceinline__ f8 load8(const float* p) {
    f8 r;
    float4 a = *(const float4*)p;
    float4 b = *(const float4*)(p + 4);
    r.v[0]=a.x; r.v[1]=a.y; r.v[2]=a.z; r.v[3]=a.w;
    r.v[4]=b.x; r.v[5]=b.y; r.v[6]=b.z; r.v[7]=b.w;
    return r;
}
__device__ __forceinline__ bf16x8 pack8(const float* h) {
    bf16x8 o;
#pragma unroll
    for (int j = 0; j < 8; ++j) o[j] = (short)f2bf(h[j]);
    return o;
}
__device__ __forceinline__ void unpack8(bf16x8 b, float* o) {
#pragma unroll
    for (int j = 0; j < 8; ++j)
        o[j] = __uint_as_float(((unsigned int)(unsigned short)b[j]) << 16);
}

// ---------------------------------------------------------------------------
// Index decode + degree histogram.
// ---------------------------------------------------------------------------
__global__ void detect_idx_kernel(const void* ei, int N, int* flag) {
    int lane = threadIdx.x;   // 64 lanes
    const long long* p64 = (const long long*)ei;
    long long v = p64[lane];
    bool ok = (v >= 0 && v < (long long)N);
    unsigned long long m = __ballot(ok);
    if (lane == 0) *flag = (m == ~0ull) ? 1 : 0;
}

__global__ void decode_idx_kernel(const void* ei, int E, int N, const int* flag,
                                  int* __restrict__ srcw, int* __restrict__ dstw,
                                  int* __restrict__ deg_i) {
    int i = blockIdx.x * blockDim.x + threadIdx.x;
    if (i >= 2 * E) return;
    int v;
    if (*flag) v = (int)((const long long*)ei)[i];
    else       v = ((const int*)ei)[i];
    v = min(max(v, 0), N - 1);
    if (i < E) {
        srcw[i] = v;
    } else {
        dstw[i - E] = v;
        atomicAdd(&deg_i[v], 1);
    }
}

// ---------------------------------------------------------------------------
// 3-phase parallel exclusive scan: deg_i -> row_start[0..N]
// ---------------------------------------------------------------------------
__global__ __launch_bounds__(256) void scan1_kernel(const int* __restrict__ deg_i,
                                                    int* __restrict__ part, int N) {
    __shared__ int wsum[4];
    int b = blockIdx.x, t = threadIdx.x;
    int base = b * CHUNK;
    int sum = 0;
    for (int i = t; i < CHUNK; i += 256) {
        int idx = base + i;
        sum += (idx < N) ? deg_i[idx] : 0;
    }
#pragma unroll
    for (int off = 32; off; off >>= 1) sum += __shfl_down(sum, off, 64);
    if ((t & 63) == 0) wsum[t >> 6] = sum;
    __syncthreads();
    if (t == 0) part[b] = wsum[0] + wsum[1] + wsum[2] + wsum[3];
}

__global__ void scan2_kernel(int* __restrict__ part, int* __restrict__ row_start,
                             int B1, int N) {
    int t = threadIdx.x;   // 64 threads
    int v = (t < B1) ? part[t] : 0;
    int incl = v;
#pragma unroll
    for (int off = 1; off < 64; off <<= 1) {
        int x = __shfl_up(incl, off, 64);
        if (t >= off) incl += x;
    }
    if (t < B1) part[t] = incl - v;      // exclusive
    if (t == 63) row_start[N] = incl;    // grand total
}

__global__ __launch_bounds__(256) void scan3_kernel(const int* __restrict__ deg_i,
                                                    const int* __restrict__ part,
                                                    int* __restrict__ row_start, int N) {
    __shared__ int wsum[4];
    __shared__ int carry_s;
    int b = blockIdx.x, t = threadIdx.x;
    int lane = t & 63, w = t >> 6;
    if (t == 0) carry_s = part[b];
    __syncthreads();
    int base0 = b * CHUNK;
    for (int base = base0; base < base0 + CHUNK; base += 256) {
        int i = base + t;
        int v = (i < N) ? deg_i[i] : 0;
        int incl = v;
#pragma unroll
        for (int off = 1; off < 64; off <<= 1) {
            int x = __shfl_up(incl, off, 64);
            if (lane >= off) incl += x;
        }
        if (lane == 63) wsum[w] = incl;
        __syncthreads();
        int wpre = 0;
#pragma unroll
        for (int k = 0; k < 4; ++k) if (k < w) wpre += wsum[k];
        int total = wsum[0] + wsum[1] + wsum[2] + wsum[3];
        int carry = carry_s;
        if (i < N) row_start[i] = carry + wpre + incl - v;
        __syncthreads();
        if (t == 0) carry_s = carry + total;
        __syncthreads();
    }
}

// ---------------------------------------------------------------------------
// Scatter: dst-sorted permutation; one packed 32B record per edge.
// ---------------------------------------------------------------------------
__global__ void scatter_kernel(const int* __restrict__ srcw, const int* __restrict__ dstw,
                               const float* __restrict__ dvec, const float* __restrict__ rvec,
                               const int* __restrict__ row_start, int* __restrict__ cursor,
                               float* __restrict__ rec, int E) {
    int e = blockIdx.x * blockDim.x + threadIdx.x;
    if (e >= E) return;
    int dd = dstw[e];
    int ofs = atomicAdd(&cursor[dd], 1);
    int pos = row_start[dd] + ofs;
    float dv = dvec[e];
    float c = 0.5f * (cosf(3.14159265358979323846f * dv * (1.0f / CUTOFF_F)) + 1.0f);
    c = (dv < CUTOFF_F) ? c : 0.0f;
    float4 r0 = make_float4(__int_as_float(srcw[e]), __int_as_float(dd), dv, c);
    float4 r1 = make_float4(rvec[(size_t)e * 3 + 0], rvec[(size_t)e * 3 + 1],
                            rvec[(size_t)e * 3 + 2], 0.0f);
    *(float4*)(rec + (size_t)pos * 8)     = r0;
    *(float4*)(rec + (size_t)pos * 8 + 4) = r1;
}

// ---------------------------------------------------------------------------
// Weight transpose+cast to bf16 [n][k] for MFMA operands.
// ---------------------------------------------------------------------------
__global__ __launch_bounds__(256) void wprep_kernel(
    const float* __restrict__ We1, const float* __restrict__ We2,
    const float* __restrict__ Wv,  const float* __restrict__ Wn1,
    const float* __restrict__ Wn2,
    unsigned short* __restrict__ We1t, unsigned short* __restrict__ We2t,
    unsigned short* __restrict__ Wvt,  unsigned short* __restrict__ Wn1t,
    unsigned short* __restrict__ Wn2t) {
    int l = blockIdx.x, t = threadIdx.x;
    const float* W2 = We2 + (size_t)l * HID * HID;
    unsigned short* T2 = We2t + (size_t)l * HID * HID;
    for (int idx = t; idx < HID * HID; idx += 256) {
        int n = idx >> 6, k = idx & 63;
        T2[n * 64 + k] = f2bf(W2[k * HID + n]);
    }
    const float* Wvl = Wv + (size_t)l * HID * 6;
    unsigned short* Tv = Wvt + (size_t)l * 16 * 64;
    for (int idx = t; idx < 16 * 64; idx += 256) {
        int n = idx >> 6, k = idx & 63;
        Tv[idx] = (n < 6) ? f2bf(Wvl[k * 6 + n]) : (unsigned short)0;
    }
    const float* W1 = We1 + (size_t)l * 257 * 64;
    unsigned short* T1 = We1t + (size_t)l * 128 * 128;
    for (int idx = t; idx < 128 * 128; idx += 256) {
        int n = idx >> 7, k = idx & 127;
        float w = (n < 64) ? W1[(size_t)k * 64 + n] : W1[(size_t)(k + 128) * 64 + (n - 64)];
        T1[n * 128 + k] = f2bf(w);
    }
    const float* Wn1l = Wn1 + (size_t)l * 192 * 64;
    unsigned short* Tn1 = Wn1t + (size_t)l * 64 * 192;
    for (int idx = t; idx < 64 * 192; idx += 256) {
        int n = idx / 192, k = idx - n * 192;
        Tn1[idx] = f2bf(Wn1l[(size_t)k * 64 + n]);
    }
    const float* Wn2l = Wn2 + (size_t)l * 64 * 128;
    unsigned short* Tn2 = Wn2t + (size_t)l * 128 * 64;
    for (int idx = t; idx < 128 * 64; idx += 256) {
        int n = idx >> 6, k = idx & 63;
        Tn2[idx] = f2bf(Wn2l[(size_t)k * 128 + n]);
    }
}

// ---------------------------------------------------------------------------
// node_pre (layer 0 only): [Pa|Pb] = s @ [We1a|We1b] (+be1 on Pa), bf16 out.
// Operand-swapped MFMA: lane owns ONE row (lm), 4 consecutive cols per reg
// -> 8B vector stores instead of 2B scalar stores.
// ---------------------------------------------------------------------------
__global__ __launch_bounds__(64) void node_pre_kernel(
    const float* __restrict__ s, const unsigned short* __restrict__ We1t,
    const float* __restrict__ be1,
    unsigned short* __restrict__ Pa, unsigned short* __restrict__ Pb, int N)
{
    __shared__ unsigned short sa[16 * 136];
    int lane = threadIdx.x;
    int n0 = blockIdx.x * 16;
    for (int idx = lane; idx < 512; idx += 64) {
        int rl = idx >> 5, c4 = (idx & 31) << 2;
        int n = n0 + rl;
        float4 val = make_float4(0.f, 0.f, 0.f, 0.f);
        if (n < N) val = *(const float4*)(s + (size_t)n * SDIM + c4);
        *(uint2*)(sa + rl * 136 + c4) = make_uint2(f2bf2(val.x, val.y), f2bf2(val.z, val.w));
    }
    __builtin_amdgcn_wave_barrier();
    int lm = lane & 15, lq = lane >> 4;
    int nr = n0 + lm;
    bool rowok = (nr < N);

    bf16x8 af[4];
#pragma unroll
    for (int kc = 0; kc < 4; ++kc)
        af[kc] = *(const bf16x8*)(sa + lm * 136 + kc * 32 + lq * 8);

#pragma unroll
    for (int ct = 0; ct < 8; ++ct) {
        f32x4 acc = {0.f, 0.f, 0.f, 0.f};
#pragma unroll
        for (int kc = 0; kc < 4; ++kc) {
            bf16x8 b = *(const bf16x8*)(We1t + (size_t)(ct * 16 + lm) * 128 + kc * 32 + lq * 8);
            acc = __builtin_amdgcn_mfma_f32_16x16x32_bf16(b, af[kc], acc, 0, 0, 0);
        }
        if (rowok) {
            if (ct < 4) {
                float4 b4 = *(const float4*)(be1 + ct * 16 + lq * 4);
                *(uint2*)(Pa + (size_t)nr * HID + ct * 16 + lq * 4) =
                    make_uint2(f2bf2(acc[0] + b4.x, acc[1] + b4.y),
                               f2bf2(acc[2] + b4.z, acc[3] + b4.w));
            } else {
                *(uint2*)(Pb + (size_t)nr * HID + (ct - 4) * 16 + lq * 4) =
                    make_uint2(f2bf2(acc[0], acc[1]), f2bf2(acc[2], acc[3]));
            }
        }
    }
}

// ---------------------------------------------------------------------------
// Fused edge kernel — per-wave, barrier-free (round-2 structure, best
// measured). Phase-2 MFMA operand-swapped: lane owns its own edge row, so
// the C multiplier is the lane-local Cr register and the hb write is one
// 8B store per 16-col block instead of 4 scalar stores.
// ---------------------------------------------------------------------------
__global__ __launch_bounds__(256) void edge_kernel(
    const float* __restrict__ rec,
    const unsigned short* __restrict__ Pa, const unsigned short* __restrict__ Pb,
    const float* __restrict__ wd,
    const unsigned short* __restrict__ We2t, const float* __restrict__ be2,
    const unsigned short* __restrict__ Wvt, const float* __restrict__ bv,
    const float* __restrict__ v,
    float* __restrict__ agg_s, float* __restrict__ agg_v, int E)
{
    __shared__ unsigned short hb[64 * 72];   // h bf16, stride 72 shorts (144B)
    __shared__ float  gl[64 * 8];
    __shared__ float  vb[64 * 12];           // v[src] rows (9 used, pad 12)
    __shared__ int    m_dst[64];
    __shared__ float4 m_r4[64];
    int t = threadIdx.x;
    int e0 = blockIdx.x * 64;
    int lane = t & 63, w = t >> 6;
    int lm = lane & 15, lq = lane >> 4;
    int m0 = w * 16, rm = m0 + lm;
    int ka = lq * 8, kb = 32 + lq * 8;

    // ---- own record from global: issues immediately ----
    int e  = e0 + rm;
    int ec = min(e, E - 1);
    float4 r0 = *(const float4*)(rec + (size_t)ec * 8);
    int srcr = __float_as_int(r0.x);
    int dstr = __float_as_int(r0.y);
    float dv = r0.z;
    float Cr = (e < E) ? r0.w : 0.0f;

    // ---- Pa/Pb gathers: on the critical path, issue ASAP ----
    const unsigned short* pa = Pa + (size_t)dstr * HID;
    const unsigned short* pb = Pb + (size_t)srcr * HID;
    bf16x8 ba0 = *(const bf16x8*)(pa + ka);
    bf16x8 bb0 = *(const bf16x8*)(pb + ka);
    bf16x8 ba1 = *(const bf16x8*)(pa + kb);
    bf16x8 bb1 = *(const bf16x8*)(pb + kb);
    f8 xw = load8(wd + ka), yw = load8(wd + kb);

    // ---- wave-local metadata staging (stride-1 SoA, conflict-free) ----
    if (lq == 0) {
        m_dst[rm] = dstr;
        m_r4[rm]  = *(const float4*)(rec + (size_t)ec * 8 + 4);
    }
    // v[src] row: lanes lq=0..2 cooperate per row, all share the same srcr
    {
        const float* vr = v + (size_t)srcr * 9;
        if (lq < 2) {
            float4_u a = *(const float4_u*)(vr + lq * 4);
            *(float4*)(vb + rm * 12 + lq * 4) = make_float4(a.x, a.y, a.z, a.w);
        } else if (lq == 2) {
            vb[rm * 12 + 8] = vr[8];
        }
    }
    // ---- prefetch Wv^T fragments (A-operand of gates MFMA) ----
    bf16x8 wv0 = *(const bf16x8*)(Wvt + (size_t)lm * 64 + ka);
    bf16x8 wv1 = *(const bf16x8*)(Wvt + (size_t)lm * 64 + kb);

    // ---- phase 1: h1 in MFMA A/B fragment layout, registers only ----
    bf16x8 afr0, afr1;
    {
        float fa[8], fb[8], h1[8];
        unpack8(ba0, fa); unpack8(bb0, fb);
#pragma unroll
        for (int j = 0; j < 8; ++j) h1[j] = silu_f(fa[j] + fb[j] + dv * xw.v[j]);
        afr0 = pack8(h1);
        unpack8(ba1, fa); unpack8(bb1, fb);
#pragma unroll
        for (int j = 0; j < 8; ++j) h1[j] = silu_f(fa[j] + fb[j] + dv * yw.v[j]);
        afr1 = pack8(h1);
    }

    // ---- phase 2 (swapped): h = silu(We2^T h1 + be2)*C -> hb, 8B stores ----
#pragma unroll
    for (int t4 = 0; t4 < 4; ++t4) {
        bf16x8 a0 = *(const bf16x8*)(We2t + (size_t)(t4 * 16 + lm) * 64 + ka);
        bf16x8 a1 = *(const bf16x8*)(We2t + (size_t)(t4 * 16 + lm) * 64 + kb);
        f32x4 a = {0.f, 0.f, 0.f, 0.f};
        a = __builtin_amdgcn_mfma_f32_16x16x32_bf16(a0, afr0, a, 0, 0, 0);
        a = __builtin_amdgcn_mfma_f32_16x16x32_bf16(a1, afr1, a, 0, 0, 0);
        float4 b4 = *(const float4*)(be2 + t4 * 16 + lq * 4);
        unsigned int p0 = f2bf2(silu_f(a[0] + b4.x) * Cr, silu_f(a[1] + b4.y) * Cr);
        unsigned int p1 = f2bf2(silu_f(a[2] + b4.z) * Cr, silu_f(a[3] + b4.w) * Cr);
        *(uint2*)(hb + rm * 72 + t4 * 16 + lq * 4) = make_uint2(p0, p1);
    }
    __builtin_amdgcn_wave_barrier();

    // ---- gates = (Wv^T @ h^T): operand-swapped MFMA, gate-major per lane ----
    {
        bf16x8 hb0 = *(const bf16x8*)(hb + rm * 72 + ka);
        bf16x8 hb1 = *(const bf16x8*)(hb + rm * 72 + kb);
        f32x4 ga = {0.f, 0.f, 0.f, 0.f};
        ga = __builtin_amdgcn_mfma_f32_16x16x32_bf16(wv0, hb0, ga, 0, 0, 0);
        ga = __builtin_amdgcn_mfma_f32_16x16x32_bf16(wv1, hb1, ga, 0, 0, 0);
        int er2 = m0 + lm;
        if (lq == 0) {
            float4_u bb = *(const float4_u*)bv;
            *(float4*)(gl + er2 * 8) =
                make_float4(ga[0] + bb.x, ga[1] + bb.y, ga[2] + bb.z, ga[3] + bb.w);
        } else if (lq == 1) {
            gl[er2 * 8 + 4] = ga[0] + bv[4];
            gl[er2 * 8 + 5] = ga[1] + bv[5];
        }
    }

    // ---- agg_s: segmented column-sum over own 16 rows (dst broadcast reads) ----
    {
        int c = lane;
        float acc = 0.f;
        int cur = m_dst[m0];
#pragma unroll 4
        for (int r = m0; r < m0 + 16; ++r) {
            int dr = m_dst[r];
            if (dr != cur) {
                atomicAdd(&agg_s[(size_t)cur * HID + c], acc);
                acc = 0.f; cur = dr;
            }
            acc += bf2f(hb[r * 72 + c]);
        }
        atomicAdd(&agg_s[(size_t)cur * HID + c], acc);
    }
    __builtin_amdgcn_wave_barrier();

    // ---- agg_v: mv = v[src]*g1 + r*g2, segmented over own 16 rows ----
    if (lane < 36) {
        int seg = lane / 9;
        int c = lane - seg * 9;
        int i = c / 3, j = c - i * 3;
        int r0v = m0 + seg * 4;
        const float* mrf = (const float*)m_r4;
        float acc = 0.f;
        int cur = m_dst[r0v];
#pragma unroll
        for (int r = 0; r < 4; ++r) {
            int rr = r0v + r;
            int dr = m_dst[rr];
            if (dr != cur) {
                atomicAdd(&agg_v[(size_t)cur * 9 + c], acc);
                acc = 0.f; cur = dr;
            }
            if (e0 + rr < E) {
                acc += vb[rr * 12 + c] * gl[rr * 8 + j]
                     + mrf[rr * 4 + i] * gl[rr * 8 + 3 + j];
            }
        }
        atomicAdd(&agg_v[(size_t)cur * 9 + c], acc);
    }
}

// ---------------------------------------------------------------------------
// Fused node kernel — 64-thread blocks, 16 rows each. Operand-swapped MFMAs
// throughout: lane owns ONE row (lm) and 4 consecutive cols per acc reg, so
// the s re-read/store are float4, Pa/Pb + LDS C-writes are 8B vectors.
// ---------------------------------------------------------------------------
__global__ __launch_bounds__(64) void node_fused_kernel(
    float* __restrict__ s, float* __restrict__ vout,
    float* __restrict__ agg_s, float* __restrict__ agg_v,
    const int* __restrict__ row_start,
    const unsigned short* __restrict__ Wn1t, const float* __restrict__ bn1,
    const unsigned short* __restrict__ Wn2t, const float* __restrict__ bn2,
    const unsigned short* __restrict__ We1tn, const float* __restrict__ be1n,
    unsigned short* __restrict__ Pa, unsigned short* __restrict__ Pb,
    int N, int do_pre)
{
    __shared__ unsigned short xa[16 * 200];  // phase A: [s|agg_s]; alias: s_new (stride 136)
    __shared__ unsigned short ub[16 * 72];
    int lane = threadIdx.x;
    int n0 = blockIdx.x * 16;

    // ---- v += agg_v / max(deg,1) ; zero agg_v (independent: issue first) ----
    for (int idx = lane; idx < 144; idx += 64) {
        int rl = idx / 9, c = idx - rl * 9;
        int n2 = n0 + rl;
        if (n2 < N) {
            float av = agg_v[(size_t)n2 * 9 + c];
            agg_v[(size_t)n2 * 9 + c] = 0.f;
            float dg = fmaxf((float)(row_start[n2 + 1] - row_start[n2]), 1.0f);
            vout[(size_t)n2 * 9 + c] += av / dg;
        }
    }

    // ---- stage [s | agg_s] as bf16 (zero agg_s after read) ----
    for (int idx = lane; idx < 512; idx += 64) {
        int rl = idx >> 5, c4 = (idx & 31) << 2;
        int n = n0 + rl;
        float4 val = make_float4(0.f, 0.f, 0.f, 0.f);
        if (n < N) val = *(const float4*)(s + (size_t)n * SDIM + c4);
        *(uint2*)(xa + rl * 200 + c4) = make_uint2(f2bf2(val.x, val.y), f2bf2(val.z, val.w));
    }
    for (int idx = lane; idx < 256; idx += 64) {
        int rl = idx >> 4, c4 = (idx & 15) << 2;
        int n = n0 + rl;
        float4 val = make_float4(0.f, 0.f, 0.f, 0.f);
        if (n < N) {
            float* ap = agg_s + (size_t)n * HID + c4;
            val = *(const float4*)ap;
            *(float4*)ap = make_float4(0.f, 0.f, 0.f, 0.f);   // zero for next layer
        }
        *(uint2*)(xa + rl * 200 + 128 + c4) = make_uint2(f2bf2(val.x, val.y), f2bf2(val.z, val.w));
    }
    __builtin_amdgcn_wave_barrier();

    int lm = lane & 15, lq = lane >> 4;
    int nr = n0 + lm;
    bool rowok = (nr < N);

    // ---- GEMM1 (swapped): u = silu(Wn1^T x + bn1), 8B LDS stores ----
    bf16x8 af[6];
#pragma unroll
    for (int kc = 0; kc < 6; ++kc)
        af[kc] = *(const bf16x8*)(xa + lm * 200 + kc * 32 + lq * 8);

#pragma unroll
    for (int ct = 0; ct < 4; ++ct) {
        f32x4 acc = {0.f, 0.f, 0.f, 0.f};
#pragma unroll
        for (int kc = 0; kc < 6; ++kc) {
            bf16x8 b = *(const bf16x8*)(Wn1t + (size_t)(ct * 16 + lm) * 192 + kc * 32 + lq * 8);
            acc = __builtin_amdgcn_mfma_f32_16x16x32_bf16(b, af[kc], acc, 0, 0, 0);
        }
        float4 b4 = *(const float4*)(bn1 + ct * 16 + lq * 4);
        unsigned int p0 = f2bf2(silu_f(acc[0] + b4.x), silu_f(acc[1] + b4.y));
        unsigned int p1 = f2bf2(silu_f(acc[2] + b4.z), silu_f(acc[3] + b4.w));
        *(uint2*)(ub + lm * 72 + ct * 16 + lq * 4) = make_uint2(p0, p1);
    }
    __builtin_amdgcn_wave_barrier();

    // ---- GEMM2 (swapped): s_new = s + Wn2^T u + bn2 ; float4 load/store ----
    unsigned short* sa = xa;   // alias (stride 136)
    bf16x8 uf[2];
#pragma unroll
    for (int kc = 0; kc < 2; ++kc)
        uf[kc] = *(const bf16x8*)(ub + lm * 72 + kc * 32 + lq * 8);

    // hoist the s re-reads ahead of the MFMAs (now vectorized float4)
    float4 sld[8];
#pragma unroll
    for (int ct = 0; ct < 8; ++ct)
        sld[ct] = rowok ? *(const float4*)(s + (size_t)nr * SDIM + ct * 16 + lq * 4)
                        : make_float4(0.f, 0.f, 0.f, 0.f);

#pragma unroll
    for (int ct = 0; ct < 8; ++ct) {
        f32x4 acc = {0.f, 0.f, 0.f, 0.f};
#pragma unroll
        for (int kc = 0; kc < 2; ++kc) {
            bf16x8 b = *(const bf16x8*)(Wn2t + (size_t)(ct * 16 + lm) * 64 + kc * 32 + lq * 8);
            acc = __builtin_amdgcn_mfma_f32_16x16x32_bf16(b, uf[kc], acc, 0, 0, 0);
        }
        float4 b4 = *(const float4*)(bn2 + ct * 16 + lq * 4);
        if (rowok) {
            float4 sv = make_float4(sld[ct].x + acc[0] + b4.x,
                                    sld[ct].y + acc[1] + b4.y,
                                    sld[ct].z + acc[2] + b4.z,
                                    sld[ct].w + acc[3] + b4.w);
            *(float4*)(s + (size_t)nr * SDIM + ct * 16 + lq * 4) = sv;
            *(uint2*)(sa + lm * 136 + ct * 16 + lq * 4) =
                make_uint2(f2bf2(sv.x, sv.y), f2bf2(sv.z, sv.w));
        } else {
            *(uint2*)(sa + lm * 136 + ct * 16 + lq * 4) = make_uint2(0u, 0u);
        }
    }
    __builtin_amdgcn_wave_barrier();

    // ---- pre-GEMM (swapped): [Pa|Pb] = We1(l+1)^T s_new, 8B stores ----
    if (do_pre) {
        bf16x8 pf[4];
#pragma unroll
        for (int kc = 0; kc < 4; ++kc)
            pf[kc] = *(const bf16x8*)(sa + lm * 136 + kc * 32 + lq * 8);

#pragma unroll
        for (int ct = 0; ct < 8; ++ct) {
            f32x4 acc = {0.f, 0.f, 0.f, 0.f};
#pragma unroll
            for (int kc = 0; kc < 4; ++kc) {
                bf16x8 b = *(const bf16x8*)(We1tn + (size_t)(ct * 16 + lm) * 128 + kc * 32 + lq * 8);
                acc = __builtin_amdgcn_mfma_f32_16x16x32_bf16(b, pf[kc], acc, 0, 0, 0);
            }
            if (rowok) {
                if (ct < 4) {
                    float4 b4 = *(const float4*)(be1n + ct * 16 + lq * 4);
                    *(uint2*)(Pa + (size_t)nr * HID + ct * 16 + lq * 4) =
                        make_uint2(f2bf2(acc[0] + b4.x, acc[1] + b4.y),
                                   f2bf2(acc[2] + b4.z, acc[3] + b4.w));
                } else {
                    *(uint2*)(Pb + (size_t)nr * HID + (ct - 4) * 16 + lq * 4) =
                        make_uint2(f2bf2(acc[0], acc[1]), f2bf2(acc[2], acc[3]));
                }
            }
        }
    }
}

extern "C" void kernel_launch(void* const* d_in, const int* in_sizes, int n_in,
                              void* d_out, int out_size, void* d_ws, size_t ws_size,
                              hipStream_t stream)
{
    const float* s_in  = (const float*)d_in[0];
    const float* v_in  = (const float*)d_in[1];
    const void*  ei    = d_in[2];
    const float* d_vec = (const float*)d_in[3];
    const float* r_vec = (const float*)d_in[4];
    const float* We1 = (const float*)d_in[6];
    const float* be1 = (const float*)d_in[7];
    const float* We2 = (const float*)d_in[8];
    const float* be2 = (const float*)d_in[9];
    const float* Wn1 = (const float*)d_in[10];
    const float* bn1 = (const float*)d_in[11];
    const float* Wn2 = (const float*)d_in[12];
    const float* bn2 = (const float*)d_in[13];
    const float* Wv  = (const float*)d_in[14];
    const float* bv  = (const float*)d_in[15];

    int N = in_sizes[0] / SDIM;
    int E = in_sizes[3];

    float* out_s = (float*)d_out;
    float* out_v = out_s + (size_t)N * SDIM;

    // ------ workspace layout (32B-aligned blocks) ------
    char* wp = (char*)d_ws;
    auto alloc = [&wp](size_t bytes) -> char* {
        char* p = wp;
        wp += (bytes + 31) & ~(size_t)31;
        return p;
    };
    float* rec       = (float*)alloc((size_t)E * 8 * 4);
    unsigned short* Pa = (unsigned short*)alloc((size_t)N * HID * 2);
    unsigned short* Pb = (unsigned short*)alloc((size_t)N * HID * 2);
    float* agg_s     = (float*)alloc((size_t)N * HID * 4);   // contiguous with agg_v
    float* agg_v     = (float*)alloc((size_t)N * 9 * 4);
    int*   deg_i     = (int*)alloc((size_t)N * 4);           // contiguous with cursor
    int*   cursor    = (int*)alloc((size_t)N * 4);
    int*   row_start = (int*)alloc((size_t)(N + 1) * 4);
    int*   part      = (int*)alloc(64 * 4);
    int*   flag      = (int*)alloc(16);
    int*   srcw      = (int*)alloc((size_t)E * 4);
    int*   dstw      = (int*)alloc((size_t)E * 4);
    unsigned short* We2t = (unsigned short*)alloc((size_t)DEPTH * HID * HID * 2);
    unsigned short* Wvt  = (unsigned short*)alloc((size_t)DEPTH * 16 * 64 * 2);
    unsigned short* We1t = (unsigned short*)alloc((size_t)DEPTH * 128 * 128 * 2);
    unsigned short* Wn1t = (unsigned short*)alloc((size_t)DEPTH * 64 * 192 * 2);
    unsigned short* Wn2t = (unsigned short*)alloc((size_t)DEPTH * 128 * 64 * 2);

    hipMemcpyAsync(out_s, s_in, (size_t)N * SDIM * sizeof(float),
                   hipMemcpyDeviceToDevice, stream);
    hipMemcpyAsync(out_v, v_in, (size_t)N * 9 * sizeof(float),
                   hipMemcpyDeviceToDevice, stream);

    // ------ one-time prep ------
    detect_idx_kernel<<<1, 64, 0, stream>>>(ei, N, flag);
    hipMemsetAsync(deg_i, 0, (size_t)N * 2 * sizeof(int), stream);    // deg_i + cursor
    hipMemsetAsync(agg_s, 0, (size_t)N * (HID + 9) * sizeof(float), stream);
    decode_idx_kernel<<<(2 * E + 255) / 256, 256, 0, stream>>>(ei, E, N, flag,
                                                               srcw, dstw, deg_i);
    int B1 = (N + CHUNK - 1) / CHUNK;
    scan1_kernel<<<B1, 256, 0, stream>>>(deg_i, part, N);
    scan2_kernel<<<1, 64, 0, stream>>>(part, row_start, B1, N);
    scan3_kernel<<<B1, 256, 0, stream>>>(deg_i, part, row_start, N);
    scatter_kernel<<<(E + 255) / 256, 256, 0, stream>>>(srcw, dstw, d_vec, r_vec,
                                                        row_start, cursor, rec, E);
    wprep_kernel<<<DEPTH, 256, 0, stream>>>(We1, We2, Wv, Wn1, Wn2,
                                            We1t, We2t, Wvt, Wn1t, Wn2t);

    int nb_n = (N + 15) / 16;
    int nb_e = (E + 63) / 64;
    node_pre_kernel<<<nb_n, 64, 0, stream>>>(out_s, We1t, be1, Pa, Pb, N);
    for (int l = 0; l < DEPTH; ++l) {
        int ln = (l + 1 < DEPTH) ? (l + 1) : 0;
        const float* We1_l = We1 + (size_t)l * 257 * 64;
        const float* be2_l = be2 + (size_t)l * 64;
        const float* bn1_l = bn1 + (size_t)l * 64;
        const float* bn2_l = bn2 + (size_t)l * 128;
        const float* bv_l  = bv  + (size_t)l * 6;
        const float* be1_n = be1 + (size_t)ln * 64;
        const unsigned short* We2t_l = We2t + (size_t)l * HID * HID;
        const unsigned short* Wvt_l  = Wvt  + (size_t)l * 16 * 64;
        const unsigned short* Wn1t_l = Wn1t + (size_t)l * 64 * 192;
        const unsigned short* Wn2t_l = Wn2t + (size_t)l * 128 * 64;
        const unsigned short* We1t_n = We1t + (size_t)ln * 128 * 128;

        edge_kernel<<<nb_e, 256, 0, stream>>>(rec, Pa, Pb,
                                              We1_l + 256 * 64,
                                              We2t_l, be2_l, Wvt_l, bv_l,
                                              out_v, agg_s, agg_v, E);
        node_fused_kernel<<<nb_n, 64, 0, stream>>>(out_s, out_v, agg_s, agg_v,
                                                   row_start,
                                                   Wn1t_l, bn1_l, Wn2t_l, bn2_l,
                                                   We1t_n, be1_n, Pa, Pb,
                                                   N, (l + 1 < DEPTH) ? 1 : 0);
    }
}